// Round 2
// baseline (534.114 us; speedup 1.0000x reference)
//
#include <hip/hip_runtime.h>
#include <hip/hip_bf16.h>

// Shifted-window attention (Swin), B=32 H=W=56 C=256 NH=8 hd=32 WS=7 SHIFT=3.
// fp32 in/out; bf16 MFMA compute.
//
// Big-workspace path (ws_size >= ~162 MB): 4 kernels
//   prep:  weights fp32->bf16; bias+mask table tab4[4 classes][8 heads][49][49] fp32
//   qkv:   per-window QKV GEMM (32x32x16 MFMA). x staged in LDS, then hoisted
//          ONCE into registers per wave (a0/a1, 128 VGPR); inner 6-tile loop is
//          pure {global weight loads -> MFMA -> stores}, fully unrolled so weight
//          loads for tile t+1 pipeline under tile t's MFMAs. V uses swapped
//          operands so the C-tile lands pre-transposed (coalesced VT stores).
//   attn:  one wave per (window, head); q/k/vt frags direct from global; softmax
//          via tab4; P through per-wave LDS; oh overwrites the q slot
//   proj:  per-window GEMM oh @ projW^T + bias, fp32 scatter with reverse shift
// Fallback (small ws): round-3 fused kernel (verbatim).

#define NTOK 49
#define DIM_ 256
#define NH_  8
#define NQKV 196608          // 768*256
#define NPRJ 65536           // 256*256
#define NTAB1 19208          // 8*49*49
#define NTAB4 (4 * NTAB1)    // 76832

// ---- workspace layout (bytes) ----
#define WSP_B  393216ull                       // after wsQ (NQKV*2)
#define TAB_B  524288ull                       // after wsP (NPRJ*2)
#define Q_B    831744ull                       // after tab4 (NTAB4*4), 256B-aligned
#define QK_EL  25690112                        // 2048*8*49*32
#define Q_BYTES 51380224ull
#define K_B    (Q_B + Q_BYTES)                 // 52,211,968
#define VT_B   (K_B + Q_BYTES)                 // 103,592,192
#define VT_BYTES 58720256ull                   // 2048*8*32*56*2
#define NEED_BIG (VT_B + VT_BYTES)             // 162,312,448
#define NEED_TAB (TAB_B + (unsigned long long)NTAB4 * 4)   // 831,616

typedef short v8s __attribute__((ext_vector_type(8)));
typedef float v4f __attribute__((ext_vector_type(4)));
typedef float v16f __attribute__((ext_vector_type(16)));

#define MFMA16 __builtin_amdgcn_mfma_f32_16x16x32_bf16
#define MFMA32 __builtin_amdgcn_mfma_f32_32x32x16_bf16
#define LGKM_WAIT() asm volatile("s_waitcnt lgkmcnt(0)" ::: "memory")

static __device__ __forceinline__ v8s zero_v8s() {
    v8s z = {0, 0, 0, 0, 0, 0, 0, 0};
    return z;
}

static __device__ __forceinline__ v16f zero_v16f() {
    v16f z;
    #pragma unroll
    for (int i = 0; i < 16; ++i) z[i] = 0.0f;
    return z;
}

static __device__ __forceinline__ v8s lds_frag(const __hip_bfloat16* p, int row,
                                               int stride, int koff, int nrows) {
    if (row < nrows) return *(const v8s*)(p + row * stride + koff);
    return zero_v8s();
}

// 8 consecutive fp32 -> 8 bf16 fragment (32B-aligned source)
static __device__ __forceinline__ v8s cvt8(const float* p) {
    v4f a = *(const v4f*)p;
    v4f b = *(const v4f*)(p + 4);
    union { v8s v; __hip_bfloat16 h[8]; } r;
    r.h[0] = __float2bfloat16(a[0]); r.h[1] = __float2bfloat16(a[1]);
    r.h[2] = __float2bfloat16(a[2]); r.h[3] = __float2bfloat16(a[3]);
    r.h[4] = __float2bfloat16(b[0]); r.h[5] = __float2bfloat16(b[1]);
    r.h[6] = __float2bfloat16(b[2]); r.h[7] = __float2bfloat16(b[3]);
    return r.v;
}

// ======================= prep =======================
__global__ __launch_bounds__(256) void prep_kernel(
    const float* __restrict__ qkvW, const float* __restrict__ projW,
    const float* __restrict__ rbt, const int* __restrict__ rpi,
    __hip_bfloat16* __restrict__ wsQ, __hip_bfloat16* __restrict__ wsP,
    float* __restrict__ tab4, int doTab)
{
    int i = blockIdx.x * 256 + threadIdx.x;
    if (i < NQKV) { wsQ[i] = __float2bfloat16(qkvW[i]); return; }
    int j = i - NQKV;
    if (j < NPRJ) { wsP[j] = __float2bfloat16(projW[j]); return; }
    int t = j - NPRJ;
    if (!doTab || t >= NTAB4) return;
    int cls = t / NTAB1, rem = t - cls * NTAB1;
    int h = rem / 2401, p = rem - h * 2401;
    int row = p / 49, col = p - row * 49;
    // region id: nonzero only on edge windows (cls bit0 = h-edge, bit1 = w-edge)
    int rh = (cls & 1) ? (((row / 7) < 4) ? 1 : 2) : 0;
    int rw = (cls & 2) ? (((row % 7) < 4) ? 1 : 2) : 0;
    int ch = (cls & 1) ? (((col / 7) < 4) ? 1 : 2) : 0;
    int cw = (cls & 2) ? (((col % 7) < 4) ? 1 : 2) : 0;
    float mask = ((rh * 3 + rw) != (ch * 3 + cw)) ? -100.0f : 0.0f;
    tab4[t] = rbt[rpi[p] * NH_ + h] + mask;
}

// ======================= phase A: QKV GEMM (32x32x16 MFMA, register-A) ==========
__global__ __launch_bounds__(256, 2) void qkv_kernel(
    const float* __restrict__ x,       // (32,56,56,256)
    const float* __restrict__ qkvB,    // (768,)
    const __hip_bfloat16* __restrict__ wsQ,  // (768,256) bf16
    __hip_bfloat16* __restrict__ Q,    // [win][h][49][32], scaled
    __hip_bfloat16* __restrict__ K,    // [win][h][49][32]
    __hip_bfloat16* __restrict__ VT)   // [win][h][32][56], cols 49..55 zero
{
    constexpr int SXS = 264;  // s_x row stride (el)
    __shared__ alignas(16) __hip_bfloat16 s_x[NTOK * SXS];   // 25,872 B

    const int tid = threadIdx.x, wave = tid >> 6, lane = tid & 63;
    const int l32 = lane & 31, half = lane >> 5;
    const int win = blockIdx.x;
    const int b = win >> 6, wh = (win >> 3) & 7, wwi = win & 7;

    // stage window x -> bf16 LDS (shifted gather), cooperative
    for (int i = tid; i < NTOK * 64; i += 256) {
        int tok = i >> 6, f4 = (i & 63) * 4;
        int r = tok / 7, c = tok - r * 7;
        int hg = wh * 7 + r + 3; if (hg >= 56) hg -= 56;
        int wg = wwi * 7 + c + 3; if (wg >= 56) wg -= 56;
        float4 v = *(const float4*)(x + ((b * 56 + hg) * 56 + wg) * DIM_ + f4);
        __hip_bfloat16* dst = s_x + tok * SXS + f4;
        dst[0] = __float2bfloat16(v.x);
        dst[1] = __float2bfloat16(v.y);
        dst[2] = __float2bfloat16(v.z);
        dst[3] = __float2bfloat16(v.w);
    }
    // zero VT pad cols 49..55 for this window
    for (int i = tid; i < 256 * 7; i += 256) {
        int fg = i / 7, col = 49 + (i - fg * 7);
        int h = fg >> 5, feat = fg & 31;
        VT[((win * NH_ + h) * 32 + feat) * 56 + col] = __float2bfloat16(0.0f);
    }
    __syncthreads();

    const float qscale = 0.17677669529663687f;  // 1/sqrt(32)
    // clamped second-tile row (tokens 32..63 -> clamp >=49 to 0; results masked)
    const int r1 = (32 + l32 < NTOK) ? (32 + l32) : 0;

    // ---- hoist A fragments into registers (one-time LDS reads) ----
    // a0: rows l32 (tokens 0..31); a1: rows 32+l32 (clamped). Index = kh*8+k.
    v8s a0[16], a1[16];
    {
        const __hip_bfloat16* arow0 = s_x + l32 * SXS + half * 8;
        const __hip_bfloat16* arow1 = s_x + r1 * SXS + half * 8;
        #pragma unroll
        for (int kh = 0; kh < 2; ++kh)
            #pragma unroll
            for (int k = 0; k < 8; ++k) {
                a0[kh * 8 + k] = *(const v8s*)(arow0 + kh * 128 + k * 16);
                a1[kh * 8 + k] = *(const v8s*)(arow1 + kh * 128 + k * 16);
            }
    }
    LGKM_WAIT();

    // ---- inner loop: pure {weight loads -> MFMA -> stores}, unrolled ----
    #pragma unroll
    for (int t = 0; t < 6; ++t) {
        const int nb = (wave * 6 + t) * 32;   // output col base, 0..767 (tile = 1 head)
        const int mat = nb >> 8;              // 0=q 1=k 2=v
        const int h = (nb >> 5) & 7;
        const __hip_bfloat16* wrow = wsQ + (nb + l32) * DIM_ + half * 8;

        v16f acc0 = zero_v16f(), acc1 = zero_v16f();

        if (mat < 2) {
            // C rows = tokens (two 32-row tiles), C cols = out features
            #pragma unroll
            for (int kh = 0; kh < 2; ++kh) {
                v8s wf[8];
                #pragma unroll
                for (int k = 0; k < 8; ++k)
                    wf[k] = *(const v8s*)(wrow + kh * 128 + k * 16);
                #pragma unroll
                for (int k = 0; k < 8; ++k) {
                    acc0 = MFMA32(a0[kh * 8 + k], wf[k], acc0, 0, 0, 0);
                    acc1 = MFMA32(a1[kh * 8 + k], wf[k], acc1, 0, 0, 0);
                }
            }
            float bias = qkvB[nb + l32];
            float sc = (mat == 0) ? qscale : 1.0f;
            __hip_bfloat16* dst = (mat == 0 ? Q : K) + (win * NH_ + h) * (NTOK * 32) + l32;
            #pragma unroll
            for (int rg = 0; rg < 16; ++rg) {
                int rowoff = (rg & 3) + 8 * (rg >> 2) + 4 * half;   // 0..31
                dst[rowoff * 32] = __float2bfloat16((acc0[rg] + bias) * sc);
                int tok1 = 32 + rowoff;
                if (tok1 < NTOK)
                    dst[tok1 * 32] = __float2bfloat16((acc1[rg] + bias) * sc);
            }
        } else {
            // swapped: A = weight rows (feat), B = x rows (tok) ->
            // C rows = features, C cols = tokens (already VT layout)
            #pragma unroll
            for (int kh = 0; kh < 2; ++kh) {
                v8s wf[8];
                #pragma unroll
                for (int k = 0; k < 8; ++k)
                    wf[k] = *(const v8s*)(wrow + kh * 128 + k * 16);
                #pragma unroll
                for (int k = 0; k < 8; ++k) {
                    acc0 = MFMA32(wf[k], a0[kh * 8 + k], acc0, 0, 0, 0);
                    acc1 = MFMA32(wf[k], a1[kh * 8 + k], acc1, 0, 0, 0);
                }
            }
            __hip_bfloat16* dst = VT + (win * NH_ + h) * (32 * 56);
            const int tok1 = 32 + l32;           // lane-varying; masked >= 49
            #pragma unroll
            for (int rg = 0; rg < 16; ++rg) {
                int feat = (rg & 3) + 8 * (rg >> 2) + 4 * half;     // 0..31
                float bias = qkvB[nb + feat];
                dst[feat * 56 + l32] = __float2bfloat16(acc0[rg] + bias);
                if (tok1 < NTOK)
                    dst[feat * 56 + tok1] = __float2bfloat16(acc1[rg] + bias);
            }
        }
    }
}

// ======================= phase B: attention =======================
__global__ __launch_bounds__(256) void attn_kernel(
    const float* __restrict__ tab4,   // [4][8][49][49] bias+mask
    const __hip_bfloat16* __restrict__ K,
    const __hip_bfloat16* __restrict__ VT,
    __hip_bfloat16* __restrict__ Q)   // in: q; out: oh (overwrites own slot)
{
    constexpr int PS = 72;
    __shared__ alignas(16) __hip_bfloat16 s_p[4][NTOK * PS];  // 28,224 B

    const int tid = threadIdx.x, wave = tid >> 6, lane = tid & 63;
    const int quad = lane >> 4, l16 = lane & 15;
    const int id = blockIdx.x * 4 + wave;      // (window, head) unit
    const int win = id >> 3, h = id & 7;
    const int wh = (win >> 3) & 7, wwi = win & 7;
    const int cls = ((wh == 7) ? 1 : 0) | ((wwi == 7) ? 2 : 0);
    const float* tabh = tab4 + (cls * NH_ + h) * 2401;
    __hip_bfloat16* qs = Q + (win * NH_ + h) * (NTOK * 32);
    const __hip_bfloat16* ks_ = K + (win * NH_ + h) * (NTOK * 32);
    const __hip_bfloat16* vts = VT + (win * NH_ + h) * (32 * 56);
    __hip_bfloat16* wp = s_p[wave];

    // A/B fragments straight from global (rows >=49 stray into the next slot;
    // those values only feed masked columns / dead rows — always finite bf16)
    v8s qa[4], kb[4];
    #pragma unroll
    for (int mt = 0; mt < 4; ++mt) {
        int tok = mt * 16 + l16;
        qa[mt] = *(const v8s*)(qs + tok * 32 + quad * 8);
        kb[mt] = *(const v8s*)(ks_ + tok * 32 + quad * 8);
    }
    v8s pb[2][2];
    #pragma unroll
    for (int nt = 0; nt < 2; ++nt) {
        const __hip_bfloat16* vr = vts + (nt * 16 + l16) * 56;
        pb[nt][0] = *(const v8s*)(vr + quad * 8);
        pb[nt][1] = (quad == 3) ? zero_v8s() : *(const v8s*)(vr + 32 + quad * 8);
    }

    // S = q k^T + tab (bias+mask); softmax -> P (bf16) in per-wave LDS
    #pragma unroll
    for (int mtile = 0; mtile < 4; ++mtile) {
        v4f sa[4];
        #pragma unroll
        for (int nt = 0; nt < 4; ++nt) {
            v4f z = {0.f, 0.f, 0.f, 0.f};
            sa[nt] = MFMA16(qa[mtile], kb[nt], z, 0, 0, 0);
        }
        #pragma unroll
        for (int rg = 0; rg < 4; ++rg) {
            int row = mtile * 16 + quad * 4 + rg;
            bool rok = row < NTOK;
            float v[4];
            float rmax = -1e30f;
            #pragma unroll
            for (int nt = 0; nt < 4; ++nt) {
                int col = nt * 16 + l16;
                float s = -1e30f;
                if (rok && col < NTOK)
                    s = sa[nt][rg] + tabh[row * 49 + col];
                v[nt] = s;
                rmax = fmaxf(rmax, s);
            }
            #pragma unroll
            for (int mm = 8; mm >= 1; mm >>= 1)
                rmax = fmaxf(rmax, __shfl_xor(rmax, mm, 64));
            float rsum = 0.f;
            #pragma unroll
            for (int nt = 0; nt < 4; ++nt) {
                float e = (v[nt] <= -1e29f) ? 0.f : __expf(v[nt] - rmax);
                v[nt] = e;
                rsum += e;
            }
            #pragma unroll
            for (int mm = 8; mm >= 1; mm >>= 1)
                rsum += __shfl_xor(rsum, mm, 64);
            if (rok) {
                float inv = 1.0f / rsum;
                #pragma unroll
                for (int nt = 0; nt < 4; ++nt)
                    wp[row * PS + nt * 16 + l16] = __float2bfloat16(v[nt] * inv);
            }
        }
    }
    LGKM_WAIT();

    // PV: oh(49x32) = P @ v ; overwrite own q slot
    #pragma unroll
    for (int mtile = 0; mtile < 4; ++mtile) {
        v8s pa0 = lds_frag(wp, mtile * 16 + l16, PS, quad * 8, NTOK);
        v8s pa1 = lds_frag(wp, mtile * 16 + l16, PS, 32 + quad * 8, NTOK);
        #pragma unroll
        for (int nt = 0; nt < 2; ++nt) {
            v4f z = {0.f, 0.f, 0.f, 0.f};
            v4f acc = MFMA16(pa0, pb[nt][0], z, 0, 0, 0);
            acc = MFMA16(pa1, pb[nt][1], acc, 0, 0, 0);
            #pragma unroll
            for (int rg = 0; rg < 4; ++rg) {
                int tok = mtile * 16 + quad * 4 + rg;
                if (tok < NTOK)
                    qs[tok * 32 + nt * 16 + l16] = __float2bfloat16(acc[rg]);
            }
        }
    }
}

// ======================= phase C: projection =======================
__global__ __launch_bounds__(256) void proj_kernel(
    const __hip_bfloat16* __restrict__ OH,   // = Q region: [win][h][49][32]
    const __hip_bfloat16* __restrict__ wsP,  // (256,256) bf16
    const float* __restrict__ projB,         // (256,)
    float* __restrict__ out)                 // (32,56,56,256)
{
    const int tid = threadIdx.x, wave = tid >> 6, lane = tid & 63;
    const int quad = lane >> 4, l16 = lane & 15;
    const int win = blockIdx.x;
    const int b = win >> 6, wh = (win >> 3) & 7, wwi = win & 7;
    const int m0 = wave * 16;

    // A-frags: K dim = 256 = 8 head-slots of 32
    const __hip_bfloat16* ohw = OH + (size_t)win * (NH_ * NTOK * 32);
    v8s af[8];
    int tokA = m0 + l16;
    #pragma unroll
    for (int ks = 0; ks < 8; ++ks)
        af[ks] = (tokA < NTOK)
                   ? *(const v8s*)(ohw + ks * (NTOK * 32) + tokA * 32 + quad * 8)
                   : zero_v8s();

    // output offsets for this lane's 4 rows (window-reverse + roll(+3))
    int ooff[4];
    #pragma unroll
    for (int rg = 0; rg < 4; ++rg) {
        int row = m0 + quad * 4 + rg;
        if (row < NTOK) {
            int r = row / 7, c = row - r * 7;
            int hg = wh * 7 + r + 3; if (hg >= 56) hg -= 56;
            int wg = wwi * 7 + c + 3; if (wg >= 56) wg -= 56;
            ooff[rg] = ((b * 56 + hg) * 56 + wg) * DIM_;
        } else ooff[rg] = -1;
    }

    #pragma unroll
    for (int t = 0; t < 16; ++t) {
        const __hip_bfloat16* wrow = wsP + (t * 16 + l16) * DIM_;
        v4f acc = {0.f, 0.f, 0.f, 0.f};
        #pragma unroll
        for (int ks = 0; ks < 8; ++ks) {
            v8s bfr = *(const v8s*)(wrow + ks * 32 + quad * 8);
            acc = MFMA16(af[ks], bfr, acc, 0, 0, 0);
        }
        float pbv = projB[t * 16 + l16];
        #pragma unroll
        for (int rg = 0; rg < 4; ++rg)
            if (ooff[rg] >= 0)
                out[ooff[rg] + t * 16 + l16] = acc[rg] + pbv;
    }
}

// ======================= fallback: round-3 fused kernel =======================
__global__ __launch_bounds__(256, 2) void swin_attn_fused(
    const float* __restrict__ x,
    const float* __restrict__ qkvB,
    const float* __restrict__ projB,
    const float* __restrict__ rbt,
    const int*   __restrict__ rpi,
    const __hip_bfloat16* __restrict__ wsQ,
    const __hip_bfloat16* __restrict__ wsP,
    const float* __restrict__ biasTab,   // class-0 rows of tab4 (bias only) or null
    float*       __restrict__ out)
{
    constexpr int QKS = 40;
    constexpr int VTS = 72;
    constexpr int PS  = 72;
    constexpr int OS  = 264;
    constexpr int WVSZ = 6224;

    __shared__ alignas(16) __hip_bfloat16 s_wv[4 * WVSZ];
    __shared__ alignas(16) __hip_bfloat16 s_o[NTOK * OS];
    __shared__ int s_off[NTOK];
    __shared__ int s_reg[NTOK];

    const int tid  = threadIdx.x;
    const int wave = tid >> 6;
    const int lane = tid & 63;
    const int quad = lane >> 4;
    const int l16  = lane & 15;

    const int wid  = blockIdx.x;
    const int b    = wid >> 6;
    const int wIdx = wid & 63;
    const int wh   = wIdx >> 3;
    const int wwi  = wIdx & 7;

    if (tid < NTOK) {
        int r = tid / 7, c = tid - r * 7;
        int hs = wh * 7 + r, ws = wwi * 7 + c;
        int hg = hs + 3; if (hg >= 56) hg -= 56;
        int wg = ws + 3; if (wg >= 56) wg -= 56;
        s_off[tid] = ((b * 56 + hg) * 56 + wg) * DIM_;
        int rh = (hs < 49) ? 0 : ((hs < 53) ? 1 : 2);
        int rw = (ws < 49) ? 0 : ((ws < 53) ? 1 : 2);
        s_reg[tid] = rh * 3 + rw;
    }

    __hip_bfloat16* wq  = s_wv + wave * WVSZ;
    __hip_bfloat16* wk  = wq + NTOK * QKS;
    __hip_bfloat16* wvt = wq + 2 * NTOK * QKS;
    __hip_bfloat16* wp  = wq;

    for (int i = lane; i < 32 * 15; i += 64) {
        int f = i / 15, kk = 49 + (i % 15);
        wvt[f * VTS + kk] = __float2bfloat16(0.0f);
    }
    __syncthreads();

    const float qscale = 0.17677669529663687f;

    for (int hp = 0; hp < 2; ++hp) {
        const int h = wave * 2 + hp;
        LGKM_WAIT();

        for (int mh = 0; mh < 2; ++mh) {
            const int mbase = mh * 32;
            v8s at[2][8];
            #pragma unroll
            for (int sub = 0; sub < 2; ++sub) {
                int tok = mbase + sub * 16 + l16;
                const float* xr = (tok < NTOK) ? (x + s_off[tok]) : nullptr;
                #pragma unroll
                for (int ks = 0; ks < 8; ++ks)
                    at[sub][ks] = xr ? cvt8(xr + ks * 32 + quad * 8) : zero_v8s();
            }
            #pragma unroll
            for (int t = 0; t < 6; ++t) {
                int mat = t >> 1, ntile = t & 1;
                int nout = mat * 256 + h * 32 + ntile * 16 + l16;
                const __hip_bfloat16* wrow = wsQ + nout * DIM_;
                v4f a0 = {0.f, 0.f, 0.f, 0.f}, a1 = {0.f, 0.f, 0.f, 0.f};
                #pragma unroll
                for (int ks = 0; ks < 8; ++ks) {
                    v8s bfr = *(const v8s*)(wrow + ks * 32 + quad * 8);
                    a0 = MFMA16(at[0][ks], bfr, a0, 0, 0, 0);
                    a1 = MFMA16(at[1][ks], bfr, a1, 0, 0, 0);
                }
                float bias  = qkvB[nout];
                float scale = (mat == 0) ? qscale : 1.0f;
                #pragma unroll
                for (int sub = 0; sub < 2; ++sub) {
                    v4f acc = sub ? a1 : a0;
                    #pragma unroll
                    for (int rg = 0; rg < 4; ++rg) {
                        int row = mbase + sub * 16 + quad * 4 + rg;
                        if (row < NTOK) {
                            float val = (acc[rg] + bias) * scale;
                            int col = ntile * 16 + l16;
                            __hip_bfloat16 bv = __float2bfloat16(val);
                            if (mat == 0)      wq[row * QKS + col] = bv;
                            else if (mat == 1) wk[row * QKS + col] = bv;
                            else               wvt[col * VTS + row] = bv;
                        }
                    }
                }
            }
        }
        LGKM_WAIT();

        v8s qa[4], kb[4];
        #pragma unroll
        for (int i = 0; i < 4; ++i) {
            qa[i] = lds_frag(wq, i * 16 + l16, QKS, quad * 8, NTOK);
            kb[i] = lds_frag(wk, i * 16 + l16, QKS, quad * 8, NTOK);
        }
        int regc[4];
        #pragma unroll
        for (int nt = 0; nt < 4; ++nt) {
            int col = nt * 16 + l16;
            regc[nt] = (col < NTOK) ? s_reg[col] : -1;
        }
        LGKM_WAIT();
        const float* tabh = biasTab ? (biasTab + h * 2401) : nullptr;
        #pragma unroll
        for (int mtile = 0; mtile < 4; ++mtile) {
            v4f sa[4];
            #pragma unroll
            for (int nt = 0; nt < 4; ++nt) {
                v4f z = {0.f, 0.f, 0.f, 0.f};
                sa[nt] = MFMA16(qa[mtile], kb[nt], z, 0, 0, 0);
            }
            #pragma unroll
            for (int rg = 0; rg < 4; ++rg) {
                int row = mtile * 16 + quad * 4 + rg;
                bool rok = row < NTOK;
                int rr = rok ? s_reg[row] : -2;
                float v[4];
                float rmax = -1e30f;
                #pragma unroll
                for (int nt = 0; nt < 4; ++nt) {
                    int col = nt * 16 + l16;
                    float s = -1e30f;
                    if (rok && col < NTOK) {
                        float bv = tabh ? tabh[row * 49 + col]
                                        : rbt[rpi[row * 49 + col] * NH_ + h];
                        s = sa[nt][rg] + bv;
                        if (rr != regc[nt]) s -= 100.0f;
                    }
                    v[nt] = s;
                    rmax = fmaxf(rmax, s);
                }
                #pragma unroll
                for (int mm = 8; mm >= 1; mm >>= 1)
                    rmax = fmaxf(rmax, __shfl_xor(rmax, mm, 64));
                float rsum = 0.f;
                #pragma unroll
                for (int nt = 0; nt < 4; ++nt) {
                    float e = (v[nt] <= -1e29f) ? 0.f : __expf(v[nt] - rmax);
                    v[nt] = e;
                    rsum += e;
                }
                #pragma unroll
                for (int mm = 8; mm >= 1; mm >>= 1)
                    rsum += __shfl_xor(rsum, mm, 64);
                if (rok) {
                    float inv = 1.0f / rsum;
                    #pragma unroll
                    for (int nt = 0; nt < 4; ++nt)
                        wp[row * PS + nt * 16 + l16] = __float2bfloat16(v[nt] * inv);
                }
            }
        }
        LGKM_WAIT();

        v8s pb[2][2];
        #pragma unroll
        for (int nt = 0; nt < 2; ++nt)
            #pragma unroll
            for (int ks = 0; ks < 2; ++ks)
                pb[nt][ks] = *(const v8s*)(wvt + (nt * 16 + l16) * VTS + ks * 32 + quad * 8);
        #pragma unroll
        for (int mtile = 0; mtile < 4; ++mtile) {
            v8s pa0 = lds_frag(wp, mtile * 16 + l16, PS, quad * 8, NTOK);
            v8s pa1 = lds_frag(wp, mtile * 16 + l16, PS, 32 + quad * 8, NTOK);
            #pragma unroll
            for (int nt = 0; nt < 2; ++nt) {
                v4f z = {0.f, 0.f, 0.f, 0.f};
                v4f acc = MFMA16(pa0, pb[nt][0], z, 0, 0, 0);
                acc = MFMA16(pa1, pb[nt][1], acc, 0, 0, 0);
                #pragma unroll
                for (int rg = 0; rg < 4; ++rg) {
                    int row = mtile * 16 + quad * 4 + rg;
                    if (row < NTOK)
                        s_o[row * OS + h * 32 + nt * 16 + l16] = __float2bfloat16(acc[rg]);
                }
            }
        }
    }
    __syncthreads();

    {
        int m0 = wave * 16;
        v8s af[8];
        #pragma unroll
        for (int ks = 0; ks < 8; ++ks)
            af[ks] = lds_frag(s_o, m0 + l16, OS, ks * 32 + quad * 8, NTOK);
        #pragma unroll
        for (int t = 0; t < 16; ++t) {
            const __hip_bfloat16* wrow = wsP + (t * 16 + l16) * DIM_;
            v4f acc = {0.f, 0.f, 0.f, 0.f};
            #pragma unroll
            for (int ks = 0; ks < 8; ++ks) {
                v8s bfr = *(const v8s*)(wrow + ks * 32 + quad * 8);
                acc = MFMA16(af[ks], bfr, acc, 0, 0, 0);
            }
            float pbv = projB[t * 16 + l16];
            #pragma unroll
            for (int rg = 0; rg < 4; ++rg) {
                int row = m0 + quad * 4 + rg;
                if (row < NTOK)
                    out[s_off[row] + t * 16 + l16] = acc[rg] + pbv;
            }
        }
    }
}

extern "C" void kernel_launch(void* const* d_in, const int* in_sizes, int n_in,
                              void* d_out, int out_size, void* d_ws, size_t ws_size,
                              hipStream_t stream) {
    const float* x     = (const float*)d_in[0];
    const float* qkvW  = (const float*)d_in[1];
    const float* qkvB  = (const float*)d_in[2];
    const float* projW = (const float*)d_in[3];
    const float* projB = (const float*)d_in[4];
    const float* rbt   = (const float*)d_in[5];
    const int*   rpi   = (const int*)d_in[6];
    float* o = (float*)d_out;

    __hip_bfloat16* wsQ = (__hip_bfloat16*)d_ws;
    __hip_bfloat16* wsP = (__hip_bfloat16*)((char*)d_ws + WSP_B);
    float* tab4         = (float*)((char*)d_ws + TAB_B);
    __hip_bfloat16* Q   = (__hip_bfloat16*)((char*)d_ws + Q_B);
    __hip_bfloat16* K   = (__hip_bfloat16*)((char*)d_ws + K_B);
    __hip_bfloat16* VT  = (__hip_bfloat16*)((char*)d_ws + VT_B);

    const int prepBlocks = (NQKV + NPRJ + NTAB4 + 255) / 256;

    if (ws_size >= NEED_BIG) {
        prep_kernel<<<prepBlocks, 256, 0, stream>>>(qkvW, projW, rbt, rpi,
                                                    wsQ, wsP, tab4, 1);
        qkv_kernel<<<2048, 256, 0, stream>>>(x, qkvB, wsQ, Q, K, VT);
        attn_kernel<<<4096, 256, 0, stream>>>(tab4, K, VT, Q);
        proj_kernel<<<2048, 256, 0, stream>>>(Q, wsP, projB, o);
    } else {
        int doTab = (ws_size >= NEED_TAB) ? 1 : 0;
        prep_kernel<<<prepBlocks, 256, 0, stream>>>(qkvW, projW, rbt, rpi,
                                                    wsQ, wsP, tab4, doTab);
        swin_attn_fused<<<2048, 256, 0, stream>>>(x, qkvB, projB, rbt, rpi,
                                                  wsQ, wsP, doTab ? tab4 : nullptr, o);
    }
}

// Round 3
// 486.595 us; speedup vs baseline: 1.0977x; 1.0977x over previous
//
#include <hip/hip_runtime.h>
#include <hip/hip_bf16.h>

// Shifted-window attention (Swin), B=32 H=W=56 C=256 NH=8 hd=32 WS=7 SHIFT=3.
// fp32 in/out; bf16 MFMA compute.
//
// Big-workspace path: 3 kernels
//   prep:    weights fp32->bf16; bias+mask table tab4[4][8][49][49] fp32
//   qkvattn: FUSED per-window QKV + attention. One block per window, 4 waves.
//            Each wave owns 2 heads end-to-end: computes q/k/vt for its heads
//            into wave-PRIVATE LDS (no barriers after x-staging), then runs
//            softmax(q k^T + tab) @ v and writes OH [win][h][49][32] bf16.
//            Eliminates the Q/K/VT HBM roundtrip (~320 MB) and one launch.
//   proj:    per-window GEMM oh @ projW^T + bias, fp32 scatter w/ reverse shift
// Fallback (small ws): round-3 fused kernel (verbatim).

#define NTOK 49
#define DIM_ 256
#define NH_  8
#define NQKV 196608          // 768*256
#define NPRJ 65536           // 256*256
#define NTAB1 19208          // 8*49*49
#define NTAB4 (4 * NTAB1)    // 76832

// ---- workspace layout (bytes) ----
#define WSP_B  393216ull                       // after wsQ (NQKV*2)
#define TAB_B  524288ull                       // after wsP (NPRJ*2)
#define Q_B    831744ull                       // after tab4 (NTAB4*4), 256B-aligned
#define Q_BYTES 51380224ull                    // 2048*8*49*32*2 (OH region)
#define K_B    (Q_B + Q_BYTES)
#define VT_B   (K_B + Q_BYTES)
#define VT_BYTES 58720256ull
#define NEED_BIG (VT_B + VT_BYTES)             // unchanged gate (162,312,448)
#define NEED_TAB (TAB_B + (unsigned long long)NTAB4 * 4)   // 831,616

typedef short v8s __attribute__((ext_vector_type(8)));
typedef float v4f __attribute__((ext_vector_type(4)));
typedef float v16f __attribute__((ext_vector_type(16)));

#define MFMA16 __builtin_amdgcn_mfma_f32_16x16x32_bf16
#define MFMA32 __builtin_amdgcn_mfma_f32_32x32x16_bf16
#define LGKM_WAIT() asm volatile("s_waitcnt lgkmcnt(0)" ::: "memory")

static __device__ __forceinline__ v8s zero_v8s() {
    v8s z = {0, 0, 0, 0, 0, 0, 0, 0};
    return z;
}

static __device__ __forceinline__ v16f zero_v16f() {
    v16f z;
    #pragma unroll
    for (int i = 0; i < 16; ++i) z[i] = 0.0f;
    return z;
}

static __device__ __forceinline__ v8s lds_frag(const __hip_bfloat16* p, int row,
                                               int stride, int koff, int nrows) {
    if (row < nrows) return *(const v8s*)(p + row * stride + koff);
    return zero_v8s();
}

// 8 consecutive fp32 -> 8 bf16 fragment (32B-aligned source)
static __device__ __forceinline__ v8s cvt8(const float* p) {
    v4f a = *(const v4f*)p;
    v4f b = *(const v4f*)(p + 4);
    union { v8s v; __hip_bfloat16 h[8]; } r;
    r.h[0] = __float2bfloat16(a[0]); r.h[1] = __float2bfloat16(a[1]);
    r.h[2] = __float2bfloat16(a[2]); r.h[3] = __float2bfloat16(a[3]);
    r.h[4] = __float2bfloat16(b[0]); r.h[5] = __float2bfloat16(b[1]);
    r.h[6] = __float2bfloat16(b[2]); r.h[7] = __float2bfloat16(b[3]);
    return r.v;
}

// ======================= prep =======================
__global__ __launch_bounds__(256) void prep_kernel(
    const float* __restrict__ qkvW, const float* __restrict__ projW,
    const float* __restrict__ rbt, const int* __restrict__ rpi,
    __hip_bfloat16* __restrict__ wsQ, __hip_bfloat16* __restrict__ wsP,
    float* __restrict__ tab4, int doTab)
{
    int i = blockIdx.x * 256 + threadIdx.x;
    if (i < NQKV) { wsQ[i] = __float2bfloat16(qkvW[i]); return; }
    int j = i - NQKV;
    if (j < NPRJ) { wsP[j] = __float2bfloat16(projW[j]); return; }
    int t = j - NPRJ;
    if (!doTab || t >= NTAB4) return;
    int cls = t / NTAB1, rem = t - cls * NTAB1;
    int h = rem / 2401, p = rem - h * 2401;
    int row = p / 49, col = p - row * 49;
    // region id: nonzero only on edge windows (cls bit0 = h-edge, bit1 = w-edge)
    int rh = (cls & 1) ? (((row / 7) < 4) ? 1 : 2) : 0;
    int rw = (cls & 2) ? (((row % 7) < 4) ? 1 : 2) : 0;
    int ch = (cls & 1) ? (((col / 7) < 4) ? 1 : 2) : 0;
    int cw = (cls & 2) ? (((col % 7) < 4) ? 1 : 2) : 0;
    float mask = ((rh * 3 + rw) != (ch * 3 + cw)) ? -100.0f : 0.0f;
    tab4[t] = rbt[rpi[p] * NH_ + h] + mask;
}

// ======================= fused QKV + attention =======================
// Per block: one window. Per wave: heads {2*wave, 2*wave+1}, fully private.
// LDS: shared s_x (x window, bf16) + 4 x per-wave {wq, wk, wvt} buffers.
// Only ONE __syncthreads (after x staging); all later phases are wave-local.
__global__ __launch_bounds__(256) void qkvattn_kernel(
    const float* __restrict__ x,       // (32,56,56,256)
    const float* __restrict__ qkvB,    // (768,)
    const __hip_bfloat16* __restrict__ wsQ,  // (768,256) bf16
    const float* __restrict__ tab4,    // [4][8][49][49] bias+mask
    __hip_bfloat16* __restrict__ OH)   // [win][h][49][32] bf16
{
    constexpr int SXS = 264;   // s_x row stride (el)
    constexpr int QKS = 40;    // wq/wk row stride (el)
    constexpr int VTS = 72;    // wvt row stride (el)
    constexpr int PS  = 72;    // P row stride (el); P overlays wq+wk
    constexpr int WVSZ = 2 * NTOK * QKS + 32 * VTS;   // 1960*2 + 2304 = 6224 el

    __shared__ alignas(16) __hip_bfloat16 s_x[NTOK * SXS];    // 25,872 B
    __shared__ alignas(16) __hip_bfloat16 s_wv[4 * WVSZ];     // 49,792 B

    const int tid = threadIdx.x, wave = tid >> 6, lane = tid & 63;
    const int quad = lane >> 4, l16 = lane & 15;
    const int l32 = lane & 31, half = lane >> 5;
    const int win = blockIdx.x;
    const int b = win >> 6, wh = (win >> 3) & 7, wwi = win & 7;
    const int cls = ((wh == 7) ? 1 : 0) | ((wwi == 7) ? 2 : 0);

    __hip_bfloat16* wq  = s_wv + wave * WVSZ;
    __hip_bfloat16* wk  = wq + NTOK * QKS;
    __hip_bfloat16* wvt = wq + 2 * NTOK * QKS;
    __hip_bfloat16* wp  = wq;                     // P overlays q+k (dead then)

    // zero wvt pad cols 49..55 (per wave; persists across both heads)
    for (int i = lane; i < 32 * 7; i += 64)
        wvt[(i / 7) * VTS + 49 + (i % 7)] = __float2bfloat16(0.0f);

    // stage window x -> bf16 LDS (shifted gather), cooperative
    for (int i = tid; i < NTOK * 64; i += 256) {
        int tok = i >> 6, f4 = (i & 63) * 4;
        int r = tok / 7, c = tok - r * 7;
        int hg = wh * 7 + r + 3; if (hg >= 56) hg -= 56;
        int wg = wwi * 7 + c + 3; if (wg >= 56) wg -= 56;
        float4 v = *(const float4*)(x + ((b * 56 + hg) * 56 + wg) * DIM_ + f4);
        __hip_bfloat16* dst = s_x + tok * SXS + f4;
        dst[0] = __float2bfloat16(v.x);
        dst[1] = __float2bfloat16(v.y);
        dst[2] = __float2bfloat16(v.z);
        dst[3] = __float2bfloat16(v.w);
    }
    __syncthreads();   // the only block-wide barrier

    const float qscale = 0.17677669529663687f;  // 1/sqrt(32)
    // clamped second-tile row (tokens 32..63 -> clamp >=49 to 0; results masked)
    const int r1 = (32 + l32 < NTOK) ? (32 + l32) : 0;
    const __hip_bfloat16* arow0 = s_x + l32 * SXS + half * 8;
    const __hip_bfloat16* arow1 = s_x + r1 * SXS + half * 8;

    for (int hp = 0; hp < 2; ++hp) {
        const int h = wave * 2 + hp;

        // ---------- QKV for head h: 3 col-tiles (q, k, v) ----------
        #pragma unroll
        for (int m = 0; m < 3; ++m) {
            const int nb = m * 256 + h * 32;
            const __hip_bfloat16* wrow = wsQ + (nb + l32) * DIM_ + half * 8;
            v16f acc0 = zero_v16f(), acc1 = zero_v16f();

            if (m < 2) {
                // C rows = tokens, C cols = out features
                #pragma unroll
                for (int kh = 0; kh < 2; ++kh) {
                    v8s wf[8];
                    #pragma unroll
                    for (int k = 0; k < 8; ++k)
                        wf[k] = *(const v8s*)(wrow + kh * 128 + k * 16);
                    #pragma unroll
                    for (int k = 0; k < 8; ++k) {
                        v8s a0 = *(const v8s*)(arow0 + kh * 128 + k * 16);
                        v8s a1 = *(const v8s*)(arow1 + kh * 128 + k * 16);
                        acc0 = MFMA32(a0, wf[k], acc0, 0, 0, 0);
                        acc1 = MFMA32(a1, wf[k], acc1, 0, 0, 0);
                    }
                }
                float bias = qkvB[nb + l32];
                float sc = (m == 0) ? qscale : 1.0f;
                __hip_bfloat16* dst = (m == 0) ? wq : wk;
                #pragma unroll
                for (int rg = 0; rg < 16; ++rg) {
                    int rowoff = (rg & 3) + 8 * (rg >> 2) + 4 * half;   // 0..31
                    dst[rowoff * QKS + l32] =
                        __float2bfloat16((acc0[rg] + bias) * sc);
                    int tok1 = 32 + rowoff;
                    if (tok1 < NTOK)
                        dst[tok1 * QKS + l32] =
                            __float2bfloat16((acc1[rg] + bias) * sc);
                }
            } else {
                // swapped operands: C rows = features, C cols = tokens (VT layout)
                #pragma unroll
                for (int kh = 0; kh < 2; ++kh) {
                    v8s wf[8];
                    #pragma unroll
                    for (int k = 0; k < 8; ++k)
                        wf[k] = *(const v8s*)(wrow + kh * 128 + k * 16);
                    #pragma unroll
                    for (int k = 0; k < 8; ++k) {
                        v8s b0 = *(const v8s*)(arow0 + kh * 128 + k * 16);
                        v8s b1 = *(const v8s*)(arow1 + kh * 128 + k * 16);
                        acc0 = MFMA32(wf[k], b0, acc0, 0, 0, 0);
                        acc1 = MFMA32(wf[k], b1, acc1, 0, 0, 0);
                    }
                }
                const int tok1 = 32 + l32;           // masked >= 49
                #pragma unroll
                for (int rg = 0; rg < 16; ++rg) {
                    int feat = (rg & 3) + 8 * (rg >> 2) + 4 * half;     // 0..31
                    float bias = qkvB[nb + feat];
                    wvt[feat * VTS + l32] = __float2bfloat16(acc0[rg] + bias);
                    if (tok1 < NTOK)
                        wvt[feat * VTS + tok1] = __float2bfloat16(acc1[rg] + bias);
                }
            }
        }
        LGKM_WAIT();   // wave-local q/k/vt writes drained before reads

        // ---------- attention head h (wave-local) ----------
        const float* tabh = tab4 + (cls * NH_ + h) * 2401;
        __hip_bfloat16* qs = OH + (win * NH_ + h) * (NTOK * 32);

        v8s qa[4], kb[4];
        #pragma unroll
        for (int mt = 0; mt < 4; ++mt) {
            qa[mt] = lds_frag(wq, mt * 16 + l16, QKS, quad * 8, NTOK);
            kb[mt] = lds_frag(wk, mt * 16 + l16, QKS, quad * 8, NTOK);
        }
        v8s pb[2][2];
        #pragma unroll
        for (int nt = 0; nt < 2; ++nt) {
            const __hip_bfloat16* vr = wvt + (nt * 16 + l16) * VTS;
            pb[nt][0] = *(const v8s*)(vr + quad * 8);
            pb[nt][1] = (quad == 3) ? zero_v8s() : *(const v8s*)(vr + 32 + quad * 8);
        }
        LGKM_WAIT();   // qa/kb/pb in regs before wp overlays wq/wk

        // S = q k^T + tab; softmax -> P (bf16) in wave LDS (overlay wq+wk)
        #pragma unroll
        for (int mtile = 0; mtile < 4; ++mtile) {
            v4f sa[4];
            #pragma unroll
            for (int nt = 0; nt < 4; ++nt) {
                v4f z = {0.f, 0.f, 0.f, 0.f};
                sa[nt] = MFMA16(qa[mtile], kb[nt], z, 0, 0, 0);
            }
            #pragma unroll
            for (int rg = 0; rg < 4; ++rg) {
                int row = mtile * 16 + quad * 4 + rg;
                bool rok = row < NTOK;
                float v[4];
                float rmax = -1e30f;
                #pragma unroll
                for (int nt = 0; nt < 4; ++nt) {
                    int col = nt * 16 + l16;
                    float s = -1e30f;
                    if (rok && col < NTOK)
                        s = sa[nt][rg] + tabh[row * 49 + col];
                    v[nt] = s;
                    rmax = fmaxf(rmax, s);
                }
                #pragma unroll
                for (int mm = 8; mm >= 1; mm >>= 1)
                    rmax = fmaxf(rmax, __shfl_xor(rmax, mm, 64));
                float rsum = 0.f;
                #pragma unroll
                for (int nt = 0; nt < 4; ++nt) {
                    float e = (v[nt] <= -1e29f) ? 0.f : __expf(v[nt] - rmax);
                    v[nt] = e;
                    rsum += e;
                }
                #pragma unroll
                for (int mm = 8; mm >= 1; mm >>= 1)
                    rsum += __shfl_xor(rsum, mm, 64);
                if (rok) {
                    float inv = 1.0f / rsum;
                    #pragma unroll
                    for (int nt = 0; nt < 4; ++nt)
                        wp[row * PS + nt * 16 + l16] = __float2bfloat16(v[nt] * inv);
                }
            }
        }
        LGKM_WAIT();

        // PV: oh(49x32) = P @ v ; store to OH global
        #pragma unroll
        for (int mtile = 0; mtile < 4; ++mtile) {
            v8s pa0 = lds_frag(wp, mtile * 16 + l16, PS, quad * 8, NTOK);
            v8s pa1 = lds_frag(wp, mtile * 16 + l16, PS, 32 + quad * 8, NTOK);
            #pragma unroll
            for (int nt = 0; nt < 2; ++nt) {
                v4f z = {0.f, 0.f, 0.f, 0.f};
                v4f acc = MFMA16(pa0, pb[nt][0], z, 0, 0, 0);
                acc = MFMA16(pa1, pb[nt][1], acc, 0, 0, 0);
                #pragma unroll
                for (int rg = 0; rg < 4; ++rg) {
                    int tok = mtile * 16 + quad * 4 + rg;
                    if (tok < NTOK)
                        qs[tok * 32 + nt * 16 + l16] = __float2bfloat16(acc[rg]);
                }
            }
        }
        LGKM_WAIT();   // P reads drained before next head overwrites buffers
    }
}

// ======================= phase C: projection =======================
__global__ __launch_bounds__(256) void proj_kernel(
    const __hip_bfloat16* __restrict__ OH,   // [win][h][49][32]
    const __hip_bfloat16* __restrict__ wsP,  // (256,256) bf16
    const float* __restrict__ projB,         // (256,)
    float* __restrict__ out)                 // (32,56,56,256)
{
    const int tid = threadIdx.x, wave = tid >> 6, lane = tid & 63;
    const int quad = lane >> 4, l16 = lane & 15;
    const int win = blockIdx.x;
    const int b = win >> 6, wh = (win >> 3) & 7, wwi = win & 7;
    const int m0 = wave * 16;

    // A-frags: K dim = 256 = 8 head-slots of 32
    const __hip_bfloat16* ohw = OH + (size_t)win * (NH_ * NTOK * 32);
    v8s af[8];
    int tokA = m0 + l16;
    #pragma unroll
    for (int ks = 0; ks < 8; ++ks)
        af[ks] = (tokA < NTOK)
                   ? *(const v8s*)(ohw + ks * (NTOK * 32) + tokA * 32 + quad * 8)
                   : zero_v8s();

    // output offsets for this lane's 4 rows (window-reverse + roll(+3))
    int ooff[4];
    #pragma unroll
    for (int rg = 0; rg < 4; ++rg) {
        int row = m0 + quad * 4 + rg;
        if (row < NTOK) {
            int r = row / 7, c = row - r * 7;
            int hg = wh * 7 + r + 3; if (hg >= 56) hg -= 56;
            int wg = wwi * 7 + c + 3; if (wg >= 56) wg -= 56;
            ooff[rg] = ((b * 56 + hg) * 56 + wg) * DIM_;
        } else ooff[rg] = -1;
    }

    #pragma unroll
    for (int t = 0; t < 16; ++t) {
        const __hip_bfloat16* wrow = wsP + (t * 16 + l16) * DIM_;
        v4f acc = {0.f, 0.f, 0.f, 0.f};
        #pragma unroll
        for (int ks = 0; ks < 8; ++ks) {
            v8s bfr = *(const v8s*)(wrow + ks * 32 + quad * 8);
            acc = MFMA16(af[ks], bfr, acc, 0, 0, 0);
        }
        float pbv = projB[t * 16 + l16];
        #pragma unroll
        for (int rg = 0; rg < 4; ++rg)
            if (ooff[rg] >= 0)
                out[ooff[rg] + t * 16 + l16] = acc[rg] + pbv;
    }
}

// ======================= fallback: round-3 fused kernel =======================
__global__ __launch_bounds__(256, 2) void swin_attn_fused(
    const float* __restrict__ x,
    const float* __restrict__ qkvB,
    const float* __restrict__ projB,
    const float* __restrict__ rbt,
    const int*   __restrict__ rpi,
    const __hip_bfloat16* __restrict__ wsQ,
    const __hip_bfloat16* __restrict__ wsP,
    const float* __restrict__ biasTab,   // class-0 rows of tab4 (bias only) or null
    float*       __restrict__ out)
{
    constexpr int QKS = 40;
    constexpr int VTS = 72;
    constexpr int PS  = 72;
    constexpr int OS  = 264;
    constexpr int WVSZ = 6224;

    __shared__ alignas(16) __hip_bfloat16 s_wv[4 * WVSZ];
    __shared__ alignas(16) __hip_bfloat16 s_o[NTOK * OS];
    __shared__ int s_off[NTOK];
    __shared__ int s_reg[NTOK];

    const int tid  = threadIdx.x;
    const int wave = tid >> 6;
    const int lane = tid & 63;
    const int quad = lane >> 4;
    const int l16  = lane & 15;

    const int wid  = blockIdx.x;
    const int b    = wid >> 6;
    const int wIdx = wid & 63;
    const int wh   = wIdx >> 3;
    const int wwi  = wIdx & 7;

    if (tid < NTOK) {
        int r = tid / 7, c = tid - r * 7;
        int hs = wh * 7 + r, ws = wwi * 7 + c;
        int hg = hs + 3; if (hg >= 56) hg -= 56;
        int wg = ws + 3; if (wg >= 56) wg -= 56;
        s_off[tid] = ((b * 56 + hg) * 56 + wg) * DIM_;
        int rh = (hs < 49) ? 0 : ((hs < 53) ? 1 : 2);
        int rw = (ws < 49) ? 0 : ((ws < 53) ? 1 : 2);
        s_reg[tid] = rh * 3 + rw;
    }

    __hip_bfloat16* wq  = s_wv + wave * WVSZ;
    __hip_bfloat16* wk  = wq + NTOK * QKS;
    __hip_bfloat16* wvt = wq + 2 * NTOK * QKS;
    __hip_bfloat16* wp  = wq;

    for (int i = lane; i < 32 * 15; i += 64) {
        int f = i / 15, kk = 49 + (i % 15);
        wvt[f * VTS + kk] = __float2bfloat16(0.0f);
    }
    __syncthreads();

    const float qscale = 0.17677669529663687f;

    for (int hp = 0; hp < 2; ++hp) {
        const int h = wave * 2 + hp;
        LGKM_WAIT();

        for (int mh = 0; mh < 2; ++mh) {
            const int mbase = mh * 32;
            v8s at[2][8];
            #pragma unroll
            for (int sub = 0; sub < 2; ++sub) {
                int tok = mbase + sub * 16 + l16;
                const float* xr = (tok < NTOK) ? (x + s_off[tok]) : nullptr;
                #pragma unroll
                for (int ks = 0; ks < 8; ++ks)
                    at[sub][ks] = xr ? cvt8(xr + ks * 32 + quad * 8) : zero_v8s();
            }
            #pragma unroll
            for (int t = 0; t < 6; ++t) {
                int mat = t >> 1, ntile = t & 1;
                int nout = mat * 256 + h * 32 + ntile * 16 + l16;
                const __hip_bfloat16* wrow = wsQ + nout * DIM_;
                v4f a0 = {0.f, 0.f, 0.f, 0.f}, a1 = {0.f, 0.f, 0.f, 0.f};
                #pragma unroll
                for (int ks = 0; ks < 8; ++ks) {
                    v8s bfr = *(const v8s*)(wrow + ks * 32 + quad * 8);
                    a0 = MFMA16(at[0][ks], bfr, a0, 0, 0, 0);
                    a1 = MFMA16(at[1][ks], bfr, a1, 0, 0, 0);
                }
                float bias  = qkvB[nout];
                float scale = (mat == 0) ? qscale : 1.0f;
                #pragma unroll
                for (int sub = 0; sub < 2; ++sub) {
                    v4f acc = sub ? a1 : a0;
                    #pragma unroll
                    for (int rg = 0; rg < 4; ++rg) {
                        int row = mbase + sub * 16 + quad * 4 + rg;
                        if (row < NTOK) {
                            float val = (acc[rg] + bias) * scale;
                            int col = ntile * 16 + l16;
                            __hip_bfloat16 bv = __float2bfloat16(val);
                            if (mat == 0)      wq[row * QKS + col] = bv;
                            else if (mat == 1) wk[row * QKS + col] = bv;
                            else               wvt[col * VTS + row] = bv;
                        }
                    }
                }
            }
        }
        LGKM_WAIT();

        v8s qa[4], kb[4];
        #pragma unroll
        for (int i = 0; i < 4; ++i) {
            qa[i] = lds_frag(wq, i * 16 + l16, QKS, quad * 8, NTOK);
            kb[i] = lds_frag(wk, i * 16 + l16, QKS, quad * 8, NTOK);
        }
        int regc[4];
        #pragma unroll
        for (int nt = 0; nt < 4; ++nt) {
            int col = nt * 16 + l16;
            regc[nt] = (col < NTOK) ? s_reg[col] : -1;
        }
        LGKM_WAIT();
        const float* tabh = biasTab ? (biasTab + h * 2401) : nullptr;
        #pragma unroll
        for (int mtile = 0; mtile < 4; ++mtile) {
            v4f sa[4];
            #pragma unroll
            for (int nt = 0; nt < 4; ++nt) {
                v4f z = {0.f, 0.f, 0.f, 0.f};
                sa[nt] = MFMA16(qa[mtile], kb[nt], z, 0, 0, 0);
            }
            #pragma unroll
            for (int rg = 0; rg < 4; ++rg) {
                int row = mtile * 16 + quad * 4 + rg;
                bool rok = row < NTOK;
                int rr = rok ? s_reg[row] : -2;
                float v[4];
                float rmax = -1e30f;
                #pragma unroll
                for (int nt = 0; nt < 4; ++nt) {
                    int col = nt * 16 + l16;
                    float s = -1e30f;
                    if (rok && col < NTOK) {
                        float bv = tabh ? tabh[row * 49 + col]
                                        : rbt[rpi[row * 49 + col] * NH_ + h];
                        s = sa[nt][rg] + bv;
                        if (rr != regc[nt]) s -= 100.0f;
                    }
                    v[nt] = s;
                    rmax = fmaxf(rmax, s);
                }
                #pragma unroll
                for (int mm = 8; mm >= 1; mm >>= 1)
                    rmax = fmaxf(rmax, __shfl_xor(rmax, mm, 64));
                float rsum = 0.f;
                #pragma unroll
                for (int nt = 0; nt < 4; ++nt) {
                    float e = (v[nt] <= -1e29f) ? 0.f : __expf(v[nt] - rmax);
                    v[nt] = e;
                    rsum += e;
                }
                #pragma unroll
                for (int mm = 8; mm >= 1; mm >>= 1)
                    rsum += __shfl_xor(rsum, mm, 64);
                if (rok) {
                    float inv = 1.0f / rsum;
                    #pragma unroll
                    for (int nt = 0; nt < 4; ++nt)
                        wp[row * PS + nt * 16 + l16] = __float2bfloat16(v[nt] * inv);
                }
            }
        }
        LGKM_WAIT();

        v8s pb[2][2];
        #pragma unroll
        for (int nt = 0; nt < 2; ++nt)
            #pragma unroll
            for (int ks = 0; ks < 2; ++ks)
                pb[nt][ks] = *(const v8s*)(wvt + (nt * 16 + l16) * VTS + ks * 32 + quad * 8);
        #pragma unroll
        for (int mtile = 0; mtile < 4; ++mtile) {
            v8s pa0 = lds_frag(wp, mtile * 16 + l16, PS, quad * 8, NTOK);
            v8s pa1 = lds_frag(wp, mtile * 16 + l16, PS, 32 + quad * 8, NTOK);
            #pragma unroll
            for (int nt = 0; nt < 2; ++nt) {
                v4f z = {0.f, 0.f, 0.f, 0.f};
                v4f acc = MFMA16(pa0, pb[nt][0], z, 0, 0, 0);
                acc = MFMA16(pa1, pb[nt][1], acc, 0, 0, 0);
                #pragma unroll
                for (int rg = 0; rg < 4; ++rg) {
                    int row = mtile * 16 + quad * 4 + rg;
                    if (row < NTOK)
                        s_o[row * OS + h * 32 + nt * 16 + l16] = __float2bfloat16(acc[rg]);
                }
            }
        }
    }
    __syncthreads();

    {
        int m0 = wave * 16;
        v8s af[8];
        #pragma unroll
        for (int ks = 0; ks < 8; ++ks)
            af[ks] = lds_frag(s_o, m0 + l16, OS, ks * 32 + quad * 8, NTOK);
        #pragma unroll
        for (int t = 0; t < 16; ++t) {
            const __hip_bfloat16* wrow = wsP + (t * 16 + l16) * DIM_;
            v4f acc = {0.f, 0.f, 0.f, 0.f};
            #pragma unroll
            for (int ks = 0; ks < 8; ++ks) {
                v8s bfr = *(const v8s*)(wrow + ks * 32 + quad * 8);
                acc = MFMA16(af[ks], bfr, acc, 0, 0, 0);
            }
            float pbv = projB[t * 16 + l16];
            #pragma unroll
            for (int rg = 0; rg < 4; ++rg) {
                int row = m0 + quad * 4 + rg;
                if (row < NTOK)
                    out[s_off[row] + t * 16 + l16] = acc[rg] + pbv;
            }
        }
    }
}

extern "C" void kernel_launch(void* const* d_in, const int* in_sizes, int n_in,
                              void* d_out, int out_size, void* d_ws, size_t ws_size,
                              hipStream_t stream) {
    const float* x     = (const float*)d_in[0];
    const float* qkvW  = (const float*)d_in[1];
    const float* qkvB  = (const float*)d_in[2];
    const float* projW = (const float*)d_in[3];
    const float* projB = (const float*)d_in[4];
    const float* rbt   = (const float*)d_in[5];
    const int*   rpi   = (const int*)d_in[6];
    float* o = (float*)d_out;

    __hip_bfloat16* wsQ = (__hip_bfloat16*)d_ws;
    __hip_bfloat16* wsP = (__hip_bfloat16*)((char*)d_ws + WSP_B);
    float* tab4         = (float*)((char*)d_ws + TAB_B);
    __hip_bfloat16* OH  = (__hip_bfloat16*)((char*)d_ws + Q_B);

    const int prepBlocks = (NQKV + NPRJ + NTAB4 + 255) / 256;

    if (ws_size >= NEED_BIG) {
        prep_kernel<<<prepBlocks, 256, 0, stream>>>(qkvW, projW, rbt, rpi,
                                                    wsQ, wsP, tab4, 1);
        qkvattn_kernel<<<2048, 256, 0, stream>>>(x, qkvB, wsQ, tab4, OH);
        proj_kernel<<<2048, 256, 0, stream>>>(OH, wsP, projB, o);
    } else {
        int doTab = (ws_size >= NEED_TAB) ? 1 : 0;
        prep_kernel<<<prepBlocks, 256, 0, stream>>>(qkvW, projW, rbt, rpi,
                                                    wsQ, wsP, tab4, doTab);
        swin_attn_fused<<<2048, 256, 0, stream>>>(x, qkvB, projB, rbt, rpi,
                                                  wsQ, wsP, doTab ? tab4 : nullptr, o);
    }
}

// Round 4
// 475.453 us; speedup vs baseline: 1.1234x; 1.0234x over previous
//
#include <hip/hip_runtime.h>
#include <hip/hip_bf16.h>

// Shifted-window attention (Swin), B=32 H=W=56 C=256 NH=8 hd=32 WS=7 SHIFT=3.
// fp32 in/out; bf16 MFMA compute.
//
// Big-workspace path: 3 kernels
//   prep:    weights fp32->bf16; padded bias+mask table tabP[4][8][64][64] fp32
//            (rows/cols >=49 filled with -1e30 -> masking is free in attn)
//   qkvattn: FUSED per-window QKV + attention. One block per window, 4 waves,
//            each wave owns 2 heads end-to-end in wave-private LDS.
//            Attention computes S^T = K·Q^T so each lane owns one q-row:
//            softmax = in-lane reduce + 2 shuffles; tab via aligned v4f loads;
//            P packed to LDS as b64 writes. Writes OH [win][h][49][32] bf16.
//   proj:    window-batched GEMM: block = (4-window group, t-quarter); weight
//            fragments loaded once per t-tile and reused across 4 windows
//            (4x fewer weight loads, inner window loop gives ILP).
// Fallback (small ws): round-3 fused kernel (tab indexing updated to 64x64).

#define NTOK 49
#define DIM_ 256
#define NH_  8
#define NQKV 196608          // 768*256
#define NPRJ 65536           // 256*256
#define NTABP 131072         // 4*8*64*64 padded table

// ---- workspace layout (bytes) ----
#define WSP_B  393216ull                       // after wsQ (NQKV*2)
#define TAB_B  524288ull                       // after wsP (NPRJ*2)
#define Q_B    1048576ull                      // after tabP (NTABP*4)
#define NEED_BIG 162312448ull                  // unchanged gate
#define NEED_TAB (TAB_B + (unsigned long long)NTABP * 4)   // 1,048,576

typedef short v8s __attribute__((ext_vector_type(8)));
typedef float v4f __attribute__((ext_vector_type(4)));
typedef float v16f __attribute__((ext_vector_type(16)));

#define MFMA16 __builtin_amdgcn_mfma_f32_16x16x32_bf16
#define MFMA32 __builtin_amdgcn_mfma_f32_32x32x16_bf16
#define LGKM_WAIT() asm volatile("s_waitcnt lgkmcnt(0)" ::: "memory")

static __device__ __forceinline__ v8s zero_v8s() {
    v8s z = {0, 0, 0, 0, 0, 0, 0, 0};
    return z;
}

static __device__ __forceinline__ v16f zero_v16f() {
    v16f z;
    #pragma unroll
    for (int i = 0; i < 16; ++i) z[i] = 0.0f;
    return z;
}

static __device__ __forceinline__ v8s lds_frag(const __hip_bfloat16* p, int row,
                                               int stride, int koff, int nrows) {
    if (row < nrows) return *(const v8s*)(p + row * stride + koff);
    return zero_v8s();
}

// 8 consecutive fp32 -> 8 bf16 fragment (32B-aligned source)
static __device__ __forceinline__ v8s cvt8(const float* p) {
    v4f a = *(const v4f*)p;
    v4f b = *(const v4f*)(p + 4);
    union { v8s v; __hip_bfloat16 h[8]; } r;
    r.h[0] = __float2bfloat16(a[0]); r.h[1] = __float2bfloat16(a[1]);
    r.h[2] = __float2bfloat16(a[2]); r.h[3] = __float2bfloat16(a[3]);
    r.h[4] = __float2bfloat16(b[0]); r.h[5] = __float2bfloat16(b[1]);
    r.h[6] = __float2bfloat16(b[2]); r.h[7] = __float2bfloat16(b[3]);
    return r.v;
}

// ======================= prep =======================
__global__ __launch_bounds__(256) void prep_kernel(
    const float* __restrict__ qkvW, const float* __restrict__ projW,
    const float* __restrict__ rbt, const int* __restrict__ rpi,
    __hip_bfloat16* __restrict__ wsQ, __hip_bfloat16* __restrict__ wsP,
    float* __restrict__ tabP, int doTab)
{
    int i = blockIdx.x * 256 + threadIdx.x;
    if (i < NQKV) { wsQ[i] = __float2bfloat16(qkvW[i]); return; }
    int j = i - NQKV;
    if (j < NPRJ) { wsP[j] = __float2bfloat16(projW[j]); return; }
    int t = j - NPRJ;
    if (!doTab || t >= NTABP) return;
    int cls = t >> 15;          // /(8*64*64)
    int rem = t & 32767;
    int h = rem >> 12;          // /4096
    int p = rem & 4095;
    int row = p >> 6, col = p & 63;
    float val = -1e30f;
    if (row < NTOK && col < NTOK) {
        // region id: nonzero only on edge windows (cls bit0=h-edge, bit1=w-edge)
        int rh = (cls & 1) ? (((row / 7) < 4) ? 1 : 2) : 0;
        int rw = (cls & 2) ? (((row % 7) < 4) ? 1 : 2) : 0;
        int ch = (cls & 1) ? (((col / 7) < 4) ? 1 : 2) : 0;
        int cw = (cls & 2) ? (((col % 7) < 4) ? 1 : 2) : 0;
        float mask = ((rh * 3 + rw) != (ch * 3 + cw)) ? -100.0f : 0.0f;
        val = rbt[rpi[row * 49 + col] * NH_ + h] + mask;
    }
    tabP[t] = val;
}

// ======================= fused QKV + attention =======================
// Per block: one window. Per wave: heads {2*wave, 2*wave+1}, fully private.
// Only ONE __syncthreads (after x staging); all later phases are wave-local.
__global__ __launch_bounds__(256) void qkvattn_kernel(
    const float* __restrict__ x,       // (32,56,56,256)
    const float* __restrict__ qkvB,    // (768,)
    const __hip_bfloat16* __restrict__ wsQ,  // (768,256) bf16
    const float* __restrict__ tabP,    // [4][8][64][64] bias+mask, padded
    __hip_bfloat16* __restrict__ OH)   // [win][h][49][32] bf16
{
    constexpr int SXS = 264;   // s_x row stride (el)
    constexpr int QKS = 40;    // wq/wk row stride (el)
    constexpr int VTS = 72;    // wvt row stride (el)
    constexpr int PS  = 72;    // P row stride (el); P overlays wq+wk
    constexpr int WVSZ = 2 * NTOK * QKS + 32 * VTS;   // 6224 el

    __shared__ alignas(16) __hip_bfloat16 s_x[NTOK * SXS];    // 25,872 B
    __shared__ alignas(16) __hip_bfloat16 s_wv[4 * WVSZ];     // 49,792 B

    const int tid = threadIdx.x, wave = tid >> 6, lane = tid & 63;
    const int quad = lane >> 4, l16 = lane & 15;
    const int l32 = lane & 31, half = lane >> 5;
    const int win = blockIdx.x;
    const int b = win >> 6, wh = (win >> 3) & 7, wwi = win & 7;
    const int cls = ((wh == 7) ? 1 : 0) | ((wwi == 7) ? 2 : 0);

    __hip_bfloat16* wq  = s_wv + wave * WVSZ;
    __hip_bfloat16* wk  = wq + NTOK * QKS;
    __hip_bfloat16* wvt = wq + 2 * NTOK * QKS;
    __hip_bfloat16* wp  = wq;                     // P overlays q+k (dead then)

    // zero wvt pad cols 49..55 (per wave; persists across both heads)
    for (int i = lane; i < 32 * 7; i += 64)
        wvt[(i / 7) * VTS + 49 + (i % 7)] = __float2bfloat16(0.0f);

    // stage window x -> bf16 LDS (shifted gather), cooperative
    for (int i = tid; i < NTOK * 64; i += 256) {
        int tok = i >> 6, f4 = (i & 63) * 4;
        int r = tok / 7, c = tok - r * 7;
        int hg = wh * 7 + r + 3; if (hg >= 56) hg -= 56;
        int wg = wwi * 7 + c + 3; if (wg >= 56) wg -= 56;
        float4 v = *(const float4*)(x + ((b * 56 + hg) * 56 + wg) * DIM_ + f4);
        __hip_bfloat16* dst = s_x + tok * SXS + f4;
        dst[0] = __float2bfloat16(v.x);
        dst[1] = __float2bfloat16(v.y);
        dst[2] = __float2bfloat16(v.z);
        dst[3] = __float2bfloat16(v.w);
    }
    __syncthreads();   // the only block-wide barrier

    const float qscale = 0.17677669529663687f;  // 1/sqrt(32)
    // clamped second-tile row (tokens 32..63 -> clamp >=49 to 0; results masked)
    const int r1 = (32 + l32 < NTOK) ? (32 + l32) : 0;
    const __hip_bfloat16* arow0 = s_x + l32 * SXS + half * 8;
    const __hip_bfloat16* arow1 = s_x + r1 * SXS + half * 8;

    for (int hp = 0; hp < 2; ++hp) {
        const int h = wave * 2 + hp;

        // ---------- QKV for head h: 3 col-tiles (q, k, v) ----------
        #pragma unroll
        for (int m = 0; m < 3; ++m) {
            const int nb = m * 256 + h * 32;
            const __hip_bfloat16* wrow = wsQ + (nb + l32) * DIM_ + half * 8;
            v16f acc0 = zero_v16f(), acc1 = zero_v16f();

            if (m < 2) {
                // C rows = tokens, C cols = out features
                #pragma unroll
                for (int kh = 0; kh < 2; ++kh) {
                    v8s wf[8];
                    #pragma unroll
                    for (int k = 0; k < 8; ++k)
                        wf[k] = *(const v8s*)(wrow + kh * 128 + k * 16);
                    #pragma unroll
                    for (int k = 0; k < 8; ++k) {
                        v8s a0 = *(const v8s*)(arow0 + kh * 128 + k * 16);
                        v8s a1 = *(const v8s*)(arow1 + kh * 128 + k * 16);
                        acc0 = MFMA32(a0, wf[k], acc0, 0, 0, 0);
                        acc1 = MFMA32(a1, wf[k], acc1, 0, 0, 0);
                    }
                }
                float bias = qkvB[nb + l32];
                float sc = (m == 0) ? qscale : 1.0f;
                __hip_bfloat16* dst = (m == 0) ? wq : wk;
                #pragma unroll
                for (int rg = 0; rg < 16; ++rg) {
                    int rowoff = (rg & 3) + 8 * (rg >> 2) + 4 * half;   // 0..31
                    dst[rowoff * QKS + l32] =
                        __float2bfloat16((acc0[rg] + bias) * sc);
                    int tok1 = 32 + rowoff;
                    if (tok1 < NTOK)
                        dst[tok1 * QKS + l32] =
                            __float2bfloat16((acc1[rg] + bias) * sc);
                }
            } else {
                // swapped operands: C rows = features, C cols = tokens (VT layout)
                #pragma unroll
                for (int kh = 0; kh < 2; ++kh) {
                    v8s wf[8];
                    #pragma unroll
                    for (int k = 0; k < 8; ++k)
                        wf[k] = *(const v8s*)(wrow + kh * 128 + k * 16);
                    #pragma unroll
                    for (int k = 0; k < 8; ++k) {
                        v8s b0 = *(const v8s*)(arow0 + kh * 128 + k * 16);
                        v8s b1 = *(const v8s*)(arow1 + kh * 128 + k * 16);
                        acc0 = MFMA32(wf[k], b0, acc0, 0, 0, 0);
                        acc1 = MFMA32(wf[k], b1, acc1, 0, 0, 0);
                    }
                }
                const int tok1 = 32 + l32;           // masked >= 49
                #pragma unroll
                for (int rg = 0; rg < 16; ++rg) {
                    int feat = (rg & 3) + 8 * (rg >> 2) + 4 * half;     // 0..31
                    float bias = qkvB[nb + feat];
                    wvt[feat * VTS + l32] = __float2bfloat16(acc0[rg] + bias);
                    if (tok1 < NTOK)
                        wvt[feat * VTS + tok1] = __float2bfloat16(acc1[rg] + bias);
                }
            }
        }
        LGKM_WAIT();   // wave-local q/k/vt writes drained before reads

        // ---------- attention head h (wave-local) ----------
        const float* tabh = tabP + (cls * NH_ + h) * 4096;   // [64][64]
        __hip_bfloat16* qs = OH + (win * NH_ + h) * (NTOK * 32);

        v8s qa[4], kb[4];
        #pragma unroll
        for (int mt = 0; mt < 4; ++mt) {
            qa[mt] = lds_frag(wq, mt * 16 + l16, QKS, quad * 8, NTOK);
            kb[mt] = lds_frag(wk, mt * 16 + l16, QKS, quad * 8, NTOK);
        }
        v8s pb[2][2];
        #pragma unroll
        for (int nt = 0; nt < 2; ++nt) {
            const __hip_bfloat16* vr = wvt + (nt * 16 + l16) * VTS;
            pb[nt][0] = *(const v8s*)(vr + quad * 8);
            pb[nt][1] = (quad == 3) ? zero_v8s() : *(const v8s*)(vr + 32 + quad * 8);
        }
        LGKM_WAIT();   // qa/kb/pb in regs before wp overlays wq/wk

        // S^T = K·Q^T: lane owns q-row (ntq*16+l16), k-values in regs.
        // softmax = in-lane reduce + 2 shuffles; P packed to LDS as b64.
        #pragma unroll
        for (int ntq = 0; ntq < 4; ++ntq) {
            const int qtok = ntq * 16 + l16;
            // prefetch bias+mask: 4 aligned v4f (padded rows make this safe)
            v4f tv[4];
            #pragma unroll
            for (int mt = 0; mt < 4; ++mt)
                tv[mt] = *(const v4f*)(tabh + qtok * 64 + mt * 16 + quad * 4);
            v4f st[4];
            #pragma unroll
            for (int mt = 0; mt < 4; ++mt) {
                v4f z = {0.f, 0.f, 0.f, 0.f};
                st[mt] = MFMA16(kb[mt], qa[ntq], z, 0, 0, 0);
            }
            float v[16];
            float rmax = -1e30f;
            #pragma unroll
            for (int mt = 0; mt < 4; ++mt)
                #pragma unroll
                for (int rg = 0; rg < 4; ++rg) {
                    float s = st[mt][rg] + tv[mt][rg];
                    v[mt * 4 + rg] = s;
                    rmax = fmaxf(rmax, s);
                }
            // lanes ^16/^32 share the same q-token (col=lane&15)
            rmax = fmaxf(rmax, __shfl_xor(rmax, 16, 64));
            rmax = fmaxf(rmax, __shfl_xor(rmax, 32, 64));
            float rsum = 0.f;
            #pragma unroll
            for (int i = 0; i < 16; ++i) {
                float e = (v[i] <= -1e29f) ? 0.f : __expf(v[i] - rmax);
                v[i] = e;
                rsum += e;
            }
            rsum += __shfl_xor(rsum, 16, 64);
            rsum += __shfl_xor(rsum, 32, 64);
            if (qtok < NTOK) {
                float inv = 1.0f / rsum;
                #pragma unroll
                for (int mt = 0; mt < 4; ++mt) {
                    union { __hip_bfloat16 h4[4]; unsigned long long u; } pk;
                    #pragma unroll
                    for (int rg = 0; rg < 4; ++rg)
                        pk.h4[rg] = __float2bfloat16(v[mt * 4 + rg] * inv);
                    *(unsigned long long*)(wp + qtok * PS + mt * 16 + quad * 4) = pk.u;
                }
            }
        }
        LGKM_WAIT();

        // PV: oh(49x32) = P @ v ; store to OH global
        #pragma unroll
        for (int mtile = 0; mtile < 4; ++mtile) {
            v8s pa0 = lds_frag(wp, mtile * 16 + l16, PS, quad * 8, NTOK);
            v8s pa1 = lds_frag(wp, mtile * 16 + l16, PS, 32 + quad * 8, NTOK);
            #pragma unroll
            for (int nt = 0; nt < 2; ++nt) {
                v4f z = {0.f, 0.f, 0.f, 0.f};
                v4f acc = MFMA16(pa0, pb[nt][0], z, 0, 0, 0);
                acc = MFMA16(pa1, pb[nt][1], acc, 0, 0, 0);
                #pragma unroll
                for (int rg = 0; rg < 4; ++rg) {
                    int tok = mtile * 16 + quad * 4 + rg;
                    if (tok < NTOK)
                        qs[tok * 32 + nt * 16 + l16] = __float2bfloat16(acc[rg]);
                }
            }
        }
        LGKM_WAIT();   // P reads drained before next head overwrites buffers
    }
}

// ======================= phase C: projection (window-batched) ==========
// block = (4-window group, t-quarter); grid 512*4 = 2048.
// Per wave: 4 t-tiles x { load wf[8] once -> 4 windows x {af[8] -> 8 MFMA} }.
__global__ __launch_bounds__(256) void proj_kernel(
    const __hip_bfloat16* __restrict__ OH,   // [win][h][49][32]
    const __hip_bfloat16* __restrict__ wsP,  // (256,256) bf16
    const float* __restrict__ projB,         // (256,)
    float* __restrict__ out)                 // (32,56,56,256)
{
    const int tid = threadIdx.x, wave = tid >> 6, lane = tid & 63;
    const int quad = lane >> 4, l16 = lane & 15;
    const int bid = blockIdx.x;
    const int wg = bid >> 2, tq = bid & 3;
    const int m0 = wave * 16;
    const int tokA = m0 + l16;

    // output offsets: 4 windows x 4 rows (window-reverse + roll(+3))
    int ooff[4][4];
    #pragma unroll
    for (int wl = 0; wl < 4; ++wl) {
        int win = wg * 4 + wl;
        int b = win >> 6, wh = (win >> 3) & 7, wwi = win & 7;
        #pragma unroll
        for (int rg = 0; rg < 4; ++rg) {
            int row = m0 + quad * 4 + rg;
            if (row < NTOK) {
                int r = row / 7, c = row - r * 7;
                int hg = wh * 7 + r + 3; if (hg >= 56) hg -= 56;
                int wgl = wwi * 7 + c + 3; if (wgl >= 56) wgl -= 56;
                ooff[wl][rg] = ((b * 56 + hg) * 56 + wgl) * DIM_;
            } else ooff[wl][rg] = -1;
        }
    }

    #pragma unroll
    for (int tt = 0; tt < 4; ++tt) {
        const int t = tq * 4 + tt;
        const __hip_bfloat16* wrow = wsP + (t * 16 + l16) * DIM_;
        v8s wf[8];
        #pragma unroll
        for (int ks = 0; ks < 8; ++ks)
            wf[ks] = *(const v8s*)(wrow + ks * 32 + quad * 8);
        float pbv = projB[t * 16 + l16];

        #pragma unroll
        for (int wl = 0; wl < 4; ++wl) {
            const __hip_bfloat16* ohw =
                OH + (size_t)(wg * 4 + wl) * (NH_ * NTOK * 32);
            v4f acc = {0.f, 0.f, 0.f, 0.f};
            #pragma unroll
            for (int ks = 0; ks < 8; ++ks) {
                v8s af = (tokA < NTOK)
                    ? *(const v8s*)(ohw + ks * (NTOK * 32) + tokA * 32 + quad * 8)
                    : zero_v8s();
                acc = MFMA16(af, wf[ks], acc, 0, 0, 0);
            }
            #pragma unroll
            for (int rg = 0; rg < 4; ++rg)
                if (ooff[wl][rg] >= 0)
                    out[ooff[wl][rg] + t * 16 + l16] = acc[rg] + pbv;
        }
    }
}

// ======================= fallback: round-3 fused kernel =======================
__global__ __launch_bounds__(256, 2) void swin_attn_fused(
    const float* __restrict__ x,
    const float* __restrict__ qkvB,
    const float* __restrict__ projB,
    const float* __restrict__ rbt,
    const int*   __restrict__ rpi,
    const __hip_bfloat16* __restrict__ wsQ,
    const __hip_bfloat16* __restrict__ wsP,
    const float* __restrict__ biasTab,   // class-0 rows of tabP (64x64) or null
    float*       __restrict__ out)
{
    constexpr int QKS = 40;
    constexpr int VTS = 72;
    constexpr int PS  = 72;
    constexpr int OS  = 264;
    constexpr int WVSZ = 6224;

    __shared__ alignas(16) __hip_bfloat16 s_wv[4 * WVSZ];
    __shared__ alignas(16) __hip_bfloat16 s_o[NTOK * OS];
    __shared__ int s_off[NTOK];
    __shared__ int s_reg[NTOK];

    const int tid  = threadIdx.x;
    const int wave = tid >> 6;
    const int lane = tid & 63;
    const int quad = lane >> 4;
    const int l16  = lane & 15;

    const int wid  = blockIdx.x;
    const int b    = wid >> 6;
    const int wIdx = wid & 63;
    const int wh   = wIdx >> 3;
    const int wwi  = wIdx & 7;

    if (tid < NTOK) {
        int r = tid / 7, c = tid - r * 7;
        int hs = wh * 7 + r, ws = wwi * 7 + c;
        int hg = hs + 3; if (hg >= 56) hg -= 56;
        int wg = ws + 3; if (wg >= 56) wg -= 56;
        s_off[tid] = ((b * 56 + hg) * 56 + wg) * DIM_;
        int rh = (hs < 49) ? 0 : ((hs < 53) ? 1 : 2);
        int rw = (ws < 49) ? 0 : ((ws < 53) ? 1 : 2);
        s_reg[tid] = rh * 3 + rw;
    }

    __hip_bfloat16* wq  = s_wv + wave * WVSZ;
    __hip_bfloat16* wk  = wq + NTOK * QKS;
    __hip_bfloat16* wvt = wq + 2 * NTOK * QKS;
    __hip_bfloat16* wp  = wq;

    for (int i = lane; i < 32 * 15; i += 64) {
        int f = i / 15, kk = 49 + (i % 15);
        wvt[f * VTS + kk] = __float2bfloat16(0.0f);
    }
    __syncthreads();

    const float qscale = 0.17677669529663687f;

    for (int hp = 0; hp < 2; ++hp) {
        const int h = wave * 2 + hp;
        LGKM_WAIT();

        for (int mh = 0; mh < 2; ++mh) {
            const int mbase = mh * 32;
            v8s at[2][8];
            #pragma unroll
            for (int sub = 0; sub < 2; ++sub) {
                int tok = mbase + sub * 16 + l16;
                const float* xr = (tok < NTOK) ? (x + s_off[tok]) : nullptr;
                #pragma unroll
                for (int ks = 0; ks < 8; ++ks)
                    at[sub][ks] = xr ? cvt8(xr + ks * 32 + quad * 8) : zero_v8s();
            }
            #pragma unroll
            for (int t = 0; t < 6; ++t) {
                int mat = t >> 1, ntile = t & 1;
                int nout = mat * 256 + h * 32 + ntile * 16 + l16;
                const __hip_bfloat16* wrow = wsQ + nout * DIM_;
                v4f a0 = {0.f, 0.f, 0.f, 0.f}, a1 = {0.f, 0.f, 0.f, 0.f};
                #pragma unroll
                for (int ks = 0; ks < 8; ++ks) {
                    v8s bfr = *(const v8s*)(wrow + ks * 32 + quad * 8);
                    a0 = MFMA16(at[0][ks], bfr, a0, 0, 0, 0);
                    a1 = MFMA16(at[1][ks], bfr, a1, 0, 0, 0);
                }
                float bias  = qkvB[nout];
                float scale = (mat == 0) ? qscale : 1.0f;
                #pragma unroll
                for (int sub = 0; sub < 2; ++sub) {
                    v4f acc = sub ? a1 : a0;
                    #pragma unroll
                    for (int rg = 0; rg < 4; ++rg) {
                        int row = mbase + sub * 16 + quad * 4 + rg;
                        if (row < NTOK) {
                            float val = (acc[rg] + bias) * scale;
                            int col = ntile * 16 + l16;
                            __hip_bfloat16 bv = __float2bfloat16(val);
                            if (mat == 0)      wq[row * QKS + col] = bv;
                            else if (mat == 1) wk[row * QKS + col] = bv;
                            else               wvt[col * VTS + row] = bv;
                        }
                    }
                }
            }
        }
        LGKM_WAIT();

        v8s qa[4], kb[4];
        #pragma unroll
        for (int i = 0; i < 4; ++i) {
            qa[i] = lds_frag(wq, i * 16 + l16, QKS, quad * 8, NTOK);
            kb[i] = lds_frag(wk, i * 16 + l16, QKS, quad * 8, NTOK);
        }
        int regc[4];
        #pragma unroll
        for (int nt = 0; nt < 4; ++nt) {
            int col = nt * 16 + l16;
            regc[nt] = (col < NTOK) ? s_reg[col] : -1;
        }
        LGKM_WAIT();
        const float* tabh = biasTab ? (biasTab + h * 4096) : nullptr;
        #pragma unroll
        for (int mtile = 0; mtile < 4; ++mtile) {
            v4f sa[4];
            #pragma unroll
            for (int nt = 0; nt < 4; ++nt) {
                v4f z = {0.f, 0.f, 0.f, 0.f};
                sa[nt] = MFMA16(qa[mtile], kb[nt], z, 0, 0, 0);
            }
            #pragma unroll
            for (int rg = 0; rg < 4; ++rg) {
                int row = mtile * 16 + quad * 4 + rg;
                bool rok = row < NTOK;
                int rr = rok ? s_reg[row] : -2;
                float v[4];
                float rmax = -1e30f;
                #pragma unroll
                for (int nt = 0; nt < 4; ++nt) {
                    int col = nt * 16 + l16;
                    float s = -1e30f;
                    if (rok && col < NTOK) {
                        float bv = tabh ? tabh[row * 64 + col]
                                        : rbt[rpi[row * 49 + col] * NH_ + h];
                        s = sa[nt][rg] + bv;
                        if (rr != regc[nt]) s -= 100.0f;
                    }
                    v[nt] = s;
                    rmax = fmaxf(rmax, s);
                }
                #pragma unroll
                for (int mm = 8; mm >= 1; mm >>= 1)
                    rmax = fmaxf(rmax, __shfl_xor(rmax, mm, 64));
                float rsum = 0.f;
                #pragma unroll
                for (int nt = 0; nt < 4; ++nt) {
                    float e = (v[nt] <= -1e29f) ? 0.f : __expf(v[nt] - rmax);
                    v[nt] = e;
                    rsum += e;
                }
                #pragma unroll
                for (int mm = 8; mm >= 1; mm >>= 1)
                    rsum += __shfl_xor(rsum, mm, 64);
                if (rok) {
                    float inv = 1.0f / rsum;
                    #pragma unroll
                    for (int nt = 0; nt < 4; ++nt)
                        wp[row * PS + nt * 16 + l16] = __float2bfloat16(v[nt] * inv);
                }
            }
        }
        LGKM_WAIT();

        v8s pb[2][2];
        #pragma unroll
        for (int nt = 0; nt < 2; ++nt)
            #pragma unroll
            for (int ks = 0; ks < 2; ++ks)
                pb[nt][ks] = *(const v8s*)(wvt + (nt * 16 + l16) * VTS + ks * 32 + quad * 8);
        #pragma unroll
        for (int mtile = 0; mtile < 4; ++mtile) {
            v8s pa0 = lds_frag(wp, mtile * 16 + l16, PS, quad * 8, NTOK);
            v8s pa1 = lds_frag(wp, mtile * 16 + l16, PS, 32 + quad * 8, NTOK);
            #pragma unroll
            for (int nt = 0; nt < 2; ++nt) {
                v4f z = {0.f, 0.f, 0.f, 0.f};
                v4f acc = MFMA16(pa0, pb[nt][0], z, 0, 0, 0);
                acc = MFMA16(pa1, pb[nt][1], acc, 0, 0, 0);
                #pragma unroll
                for (int rg = 0; rg < 4; ++rg) {
                    int row = mtile * 16 + quad * 4 + rg;
                    if (row < NTOK)
                        s_o[row * OS + h * 32 + nt * 16 + l16] = __float2bfloat16(acc[rg]);
                }
            }
        }
    }
    __syncthreads();

    {
        int m0 = wave * 16;
        v8s af[8];
        #pragma unroll
        for (int ks = 0; ks < 8; ++ks)
            af[ks] = lds_frag(s_o, m0 + l16, OS, ks * 32 + quad * 8, NTOK);
        #pragma unroll
        for (int t = 0; t < 16; ++t) {
            const __hip_bfloat16* wrow = wsP + (t * 16 + l16) * DIM_;
            v4f acc = {0.f, 0.f, 0.f, 0.f};
            #pragma unroll
            for (int ks = 0; ks < 8; ++ks) {
                v8s bfr = *(const v8s*)(wrow + ks * 32 + quad * 8);
                acc = MFMA16(af[ks], bfr, acc, 0, 0, 0);
            }
            float pbv = projB[t * 16 + l16];
            #pragma unroll
            for (int rg = 0; rg < 4; ++rg) {
                int row = m0 + quad * 4 + rg;
                if (row < NTOK)
                    out[s_off[row] + t * 16 + l16] = acc[rg] + pbv;
            }
        }
    }
}

extern "C" void kernel_launch(void* const* d_in, const int* in_sizes, int n_in,
                              void* d_out, int out_size, void* d_ws, size_t ws_size,
                              hipStream_t stream) {
    const float* x     = (const float*)d_in[0];
    const float* qkvW  = (const float*)d_in[1];
    const float* qkvB  = (const float*)d_in[2];
    const float* projW = (const float*)d_in[3];
    const float* projB = (const float*)d_in[4];
    const float* rbt   = (const float*)d_in[5];
    const int*   rpi   = (const int*)d_in[6];
    float* o = (float*)d_out;

    __hip_bfloat16* wsQ = (__hip_bfloat16*)d_ws;
    __hip_bfloat16* wsP = (__hip_bfloat16*)((char*)d_ws + WSP_B);
    float* tabP         = (float*)((char*)d_ws + TAB_B);
    __hip_bfloat16* OH  = (__hip_bfloat16*)((char*)d_ws + Q_B);

    const int prepBlocks = (NQKV + NPRJ + NTABP + 255) / 256;

    if (ws_size >= NEED_BIG) {
        prep_kernel<<<prepBlocks, 256, 0, stream>>>(qkvW, projW, rbt, rpi,
                                                    wsQ, wsP, tabP, 1);
        qkvattn_kernel<<<2048, 256, 0, stream>>>(x, qkvB, wsQ, tabP, OH);
        proj_kernel<<<2048, 256, 0, stream>>>(OH, wsP, projB, o);
    } else {
        int doTab = (ws_size >= NEED_TAB) ? 1 : 0;
        prep_kernel<<<prepBlocks, 256, 0, stream>>>(qkvW, projW, rbt, rpi,
                                                    wsQ, wsP, tabP, doTab);
        swin_attn_fused<<<2048, 256, 0, stream>>>(x, qkvB, projB, rbt, rpi,
                                                  wsQ, wsP, doTab ? tabP : nullptr, o);
    }
}

// Round 5
// 466.994 us; speedup vs baseline: 1.1437x; 1.0181x over previous
//
#include <hip/hip_runtime.h>
#include <hip/hip_bf16.h>

// Shifted-window attention (Swin), B=32 H=W=56 C=256 NH=8 hd=32 WS=7 SHIFT=3.
// fp32 in/out; bf16 MFMA compute.
//
// Big-workspace path: 3 kernels
//   prep:    weights fp32->bf16; padded bias+mask table tabP[4][8][64][64] fp32
//            (rows/cols >=49 filled with -1e30 -> masking is free in attn)
//   qkvattn: FUSED per-window QKV + attention. One block per window, 4 waves,
//            each wave owns 2 heads end-to-end in wave-private LDS.
//            S^T = K·Q^T softmax (in-lane reduce + 2 shuffles), padded tab via
//            aligned v4f loads, P packed to LDS as b64. OH [win][h][49][32].
//   proj:    latency-split GEMM: block = (window, t-quadrant), grid 8192.
//            af[8] in regs once; 4 t-tiles of {wf loads -> 8 MFMA -> store}.
//            Sibling blocks of one window mapped to the SAME XCD (bid bits 0-2
//            preserved) so the window's OH tile is fetched from HBM once.
// Fallback (small ws): fused kernel (tab indexing 64x64).

#define NTOK 49
#define DIM_ 256
#define NH_  8
#define NQKV 196608          // 768*256
#define NPRJ 65536           // 256*256
#define NTABP 131072         // 4*8*64*64 padded table

// ---- workspace layout (bytes) ----
#define WSP_B  393216ull                       // after wsQ (NQKV*2)
#define TAB_B  524288ull                       // after wsP (NPRJ*2)
#define Q_B    1048576ull                      // after tabP (NTABP*4)
#define NEED_BIG 162312448ull                  // unchanged gate
#define NEED_TAB (TAB_B + (unsigned long long)NTABP * 4)   // 1,048,576

typedef short v8s __attribute__((ext_vector_type(8)));
typedef float v4f __attribute__((ext_vector_type(4)));
typedef float v16f __attribute__((ext_vector_type(16)));

#define MFMA16 __builtin_amdgcn_mfma_f32_16x16x32_bf16
#define MFMA32 __builtin_amdgcn_mfma_f32_32x32x16_bf16
#define LGKM_WAIT() asm volatile("s_waitcnt lgkmcnt(0)" ::: "memory")

static __device__ __forceinline__ v8s zero_v8s() {
    v8s z = {0, 0, 0, 0, 0, 0, 0, 0};
    return z;
}

static __device__ __forceinline__ v16f zero_v16f() {
    v16f z;
    #pragma unroll
    for (int i = 0; i < 16; ++i) z[i] = 0.0f;
    return z;
}

static __device__ __forceinline__ v8s lds_frag(const __hip_bfloat16* p, int row,
                                               int stride, int koff, int nrows) {
    if (row < nrows) return *(const v8s*)(p + row * stride + koff);
    return zero_v8s();
}

// 8 consecutive fp32 -> 8 bf16 fragment (32B-aligned source)
static __device__ __forceinline__ v8s cvt8(const float* p) {
    v4f a = *(const v4f*)p;
    v4f b = *(const v4f*)(p + 4);
    union { v8s v; __hip_bfloat16 h[8]; } r;
    r.h[0] = __float2bfloat16(a[0]); r.h[1] = __float2bfloat16(a[1]);
    r.h[2] = __float2bfloat16(a[2]); r.h[3] = __float2bfloat16(a[3]);
    r.h[4] = __float2bfloat16(b[0]); r.h[5] = __float2bfloat16(b[1]);
    r.h[6] = __float2bfloat16(b[2]); r.h[7] = __float2bfloat16(b[3]);
    return r.v;
}

// ======================= prep =======================
__global__ __launch_bounds__(256) void prep_kernel(
    const float* __restrict__ qkvW, const float* __restrict__ projW,
    const float* __restrict__ rbt, const int* __restrict__ rpi,
    __hip_bfloat16* __restrict__ wsQ, __hip_bfloat16* __restrict__ wsP,
    float* __restrict__ tabP, int doTab)
{
    int i = blockIdx.x * 256 + threadIdx.x;
    if (i < NQKV) { wsQ[i] = __float2bfloat16(qkvW[i]); return; }
    int j = i - NQKV;
    if (j < NPRJ) { wsP[j] = __float2bfloat16(projW[j]); return; }
    int t = j - NPRJ;
    if (!doTab || t >= NTABP) return;
    int cls = t >> 15;          // /(8*64*64)
    int rem = t & 32767;
    int h = rem >> 12;          // /4096
    int p = rem & 4095;
    int row = p >> 6, col = p & 63;
    float val = -1e30f;
    if (row < NTOK && col < NTOK) {
        // region id: nonzero only on edge windows (cls bit0=h-edge, bit1=w-edge)
        int rh = (cls & 1) ? (((row / 7) < 4) ? 1 : 2) : 0;
        int rw = (cls & 2) ? (((row % 7) < 4) ? 1 : 2) : 0;
        int ch = (cls & 1) ? (((col / 7) < 4) ? 1 : 2) : 0;
        int cw = (cls & 2) ? (((col % 7) < 4) ? 1 : 2) : 0;
        float mask = ((rh * 3 + rw) != (ch * 3 + cw)) ? -100.0f : 0.0f;
        val = rbt[rpi[row * 49 + col] * NH_ + h] + mask;
    }
    tabP[t] = val;
}

// ======================= fused QKV + attention =======================
// Per block: one window. Per wave: heads {2*wave, 2*wave+1}, fully private.
// Only ONE __syncthreads (after x staging); all later phases are wave-local.
__global__ __launch_bounds__(256) void qkvattn_kernel(
    const float* __restrict__ x,       // (32,56,56,256)
    const float* __restrict__ qkvB,    // (768,)
    const __hip_bfloat16* __restrict__ wsQ,  // (768,256) bf16
    const float* __restrict__ tabP,    // [4][8][64][64] bias+mask, padded
    __hip_bfloat16* __restrict__ OH)   // [win][h][49][32] bf16
{
    constexpr int SXS = 264;   // s_x row stride (el)
    constexpr int QKS = 40;    // wq/wk row stride (el)
    constexpr int VTS = 72;    // wvt row stride (el)
    constexpr int PS  = 72;    // P row stride (el); P overlays wq+wk
    constexpr int WVSZ = 2 * NTOK * QKS + 32 * VTS;   // 6224 el

    __shared__ alignas(16) __hip_bfloat16 s_x[NTOK * SXS];    // 25,872 B
    __shared__ alignas(16) __hip_bfloat16 s_wv[4 * WVSZ];     // 49,792 B

    const int tid = threadIdx.x, wave = tid >> 6, lane = tid & 63;
    const int quad = lane >> 4, l16 = lane & 15;
    const int l32 = lane & 31, half = lane >> 5;
    const int win = blockIdx.x;
    const int b = win >> 6, wh = (win >> 3) & 7, wwi = win & 7;
    const int cls = ((wh == 7) ? 1 : 0) | ((wwi == 7) ? 2 : 0);

    __hip_bfloat16* wq  = s_wv + wave * WVSZ;
    __hip_bfloat16* wk  = wq + NTOK * QKS;
    __hip_bfloat16* wvt = wq + 2 * NTOK * QKS;
    __hip_bfloat16* wp  = wq;                     // P overlays q+k (dead then)

    // zero wvt pad cols 49..55 (per wave; persists across both heads)
    for (int i = lane; i < 32 * 7; i += 64)
        wvt[(i / 7) * VTS + 49 + (i % 7)] = __float2bfloat16(0.0f);

    // stage window x -> bf16 LDS (shifted gather), cooperative, packed 8B stores
    for (int i = tid; i < NTOK * 64; i += 256) {
        int tok = i >> 6, f4 = (i & 63) * 4;
        int r = tok / 7, c = tok - r * 7;
        int hg = wh * 7 + r + 3; if (hg >= 56) hg -= 56;
        int wg = wwi * 7 + c + 3; if (wg >= 56) wg -= 56;
        float4 v = *(const float4*)(x + ((b * 56 + hg) * 56 + wg) * DIM_ + f4);
        union { ushort4 u4; __hip_bfloat16 h[4]; } pkst;
        pkst.h[0] = __float2bfloat16(v.x);
        pkst.h[1] = __float2bfloat16(v.y);
        pkst.h[2] = __float2bfloat16(v.z);
        pkst.h[3] = __float2bfloat16(v.w);
        *(ushort4*)(s_x + tok * SXS + f4) = pkst.u4;   // 8B aligned (SXS mult of 8)
    }
    __syncthreads();   // the only block-wide barrier

    const float qscale = 0.17677669529663687f;  // 1/sqrt(32)
    // clamped second-tile row (tokens 32..63 -> clamp >=49 to 0; results masked)
    const int r1 = (32 + l32 < NTOK) ? (32 + l32) : 0;
    const __hip_bfloat16* arow0 = s_x + l32 * SXS + half * 8;
    const __hip_bfloat16* arow1 = s_x + r1 * SXS + half * 8;

    for (int hp = 0; hp < 2; ++hp) {
        const int h = wave * 2 + hp;

        // ---------- QKV for head h: 3 col-tiles (q, k, v) ----------
        #pragma unroll
        for (int m = 0; m < 3; ++m) {
            const int nb = m * 256 + h * 32;
            const __hip_bfloat16* wrow = wsQ + (nb + l32) * DIM_ + half * 8;
            v16f acc0 = zero_v16f(), acc1 = zero_v16f();

            if (m < 2) {
                // C rows = tokens, C cols = out features
                #pragma unroll
                for (int kh = 0; kh < 2; ++kh) {
                    v8s wf[8];
                    #pragma unroll
                    for (int k = 0; k < 8; ++k)
                        wf[k] = *(const v8s*)(wrow + kh * 128 + k * 16);
                    #pragma unroll
                    for (int k = 0; k < 8; ++k) {
                        v8s a0 = *(const v8s*)(arow0 + kh * 128 + k * 16);
                        v8s a1 = *(const v8s*)(arow1 + kh * 128 + k * 16);
                        acc0 = MFMA32(a0, wf[k], acc0, 0, 0, 0);
                        acc1 = MFMA32(a1, wf[k], acc1, 0, 0, 0);
                    }
                }
                float bias = qkvB[nb + l32];
                float sc = (m == 0) ? qscale : 1.0f;
                __hip_bfloat16* dst = (m == 0) ? wq : wk;
                #pragma unroll
                for (int rg = 0; rg < 16; ++rg) {
                    int rowoff = (rg & 3) + 8 * (rg >> 2) + 4 * half;   // 0..31
                    dst[rowoff * QKS + l32] =
                        __float2bfloat16((acc0[rg] + bias) * sc);
                    int tok1 = 32 + rowoff;
                    if (tok1 < NTOK)
                        dst[tok1 * QKS + l32] =
                            __float2bfloat16((acc1[rg] + bias) * sc);
                }
            } else {
                // swapped operands: C rows = features, C cols = tokens (VT layout)
                #pragma unroll
                for (int kh = 0; kh < 2; ++kh) {
                    v8s wf[8];
                    #pragma unroll
                    for (int k = 0; k < 8; ++k)
                        wf[k] = *(const v8s*)(wrow + kh * 128 + k * 16);
                    #pragma unroll
                    for (int k = 0; k < 8; ++k) {
                        v8s b0 = *(const v8s*)(arow0 + kh * 128 + k * 16);
                        v8s b1 = *(const v8s*)(arow1 + kh * 128 + k * 16);
                        acc0 = MFMA32(wf[k], b0, acc0, 0, 0, 0);
                        acc1 = MFMA32(wf[k], b1, acc1, 0, 0, 0);
                    }
                }
                const int tok1 = 32 + l32;           // masked >= 49
                #pragma unroll
                for (int rg = 0; rg < 16; ++rg) {
                    int feat = (rg & 3) + 8 * (rg >> 2) + 4 * half;     // 0..31
                    float bias = qkvB[nb + feat];
                    wvt[feat * VTS + l32] = __float2bfloat16(acc0[rg] + bias);
                    if (tok1 < NTOK)
                        wvt[feat * VTS + tok1] = __float2bfloat16(acc1[rg] + bias);
                }
            }
        }
        LGKM_WAIT();   // wave-local q/k/vt writes drained before reads

        // ---------- attention head h (wave-local) ----------
        const float* tabh = tabP + (cls * NH_ + h) * 4096;   // [64][64]
        __hip_bfloat16* qs = OH + (win * NH_ + h) * (NTOK * 32);

        v8s qa[4], kb[4];
        #pragma unroll
        for (int mt = 0; mt < 4; ++mt) {
            qa[mt] = lds_frag(wq, mt * 16 + l16, QKS, quad * 8, NTOK);
            kb[mt] = lds_frag(wk, mt * 16 + l16, QKS, quad * 8, NTOK);
        }
        v8s pb[2][2];
        #pragma unroll
        for (int nt = 0; nt < 2; ++nt) {
            const __hip_bfloat16* vr = wvt + (nt * 16 + l16) * VTS;
            pb[nt][0] = *(const v8s*)(vr + quad * 8);
            pb[nt][1] = (quad == 3) ? zero_v8s() : *(const v8s*)(vr + 32 + quad * 8);
        }
        LGKM_WAIT();   // qa/kb/pb in regs before wp overlays wq/wk

        // S^T = K·Q^T: lane owns q-row (ntq*16+l16), k-values in regs.
        // softmax = in-lane reduce + 2 shuffles; P packed to LDS as b64.
        #pragma unroll
        for (int ntq = 0; ntq < 4; ++ntq) {
            const int qtok = ntq * 16 + l16;
            // prefetch bias+mask: 4 aligned v4f (padded rows make this safe)
            v4f tv[4];
            #pragma unroll
            for (int mt = 0; mt < 4; ++mt)
                tv[mt] = *(const v4f*)(tabh + qtok * 64 + mt * 16 + quad * 4);
            v4f st[4];
            #pragma unroll
            for (int mt = 0; mt < 4; ++mt) {
                v4f z = {0.f, 0.f, 0.f, 0.f};
                st[mt] = MFMA16(kb[mt], qa[ntq], z, 0, 0, 0);
            }
            float v[16];
            float rmax = -1e30f;
            #pragma unroll
            for (int mt = 0; mt < 4; ++mt)
                #pragma unroll
                for (int rg = 0; rg < 4; ++rg) {
                    float s = st[mt][rg] + tv[mt][rg];
                    v[mt * 4 + rg] = s;
                    rmax = fmaxf(rmax, s);
                }
            // lanes ^16/^32 share the same q-token (col=lane&15)
            rmax = fmaxf(rmax, __shfl_xor(rmax, 16, 64));
            rmax = fmaxf(rmax, __shfl_xor(rmax, 32, 64));
            float rsum = 0.f;
            #pragma unroll
            for (int i = 0; i < 16; ++i) {
                float e = (v[i] <= -1e29f) ? 0.f : __expf(v[i] - rmax);
                v[i] = e;
                rsum += e;
            }
            rsum += __shfl_xor(rsum, 16, 64);
            rsum += __shfl_xor(rsum, 32, 64);
            if (qtok < NTOK) {
                float inv = 1.0f / rsum;
                #pragma unroll
                for (int mt = 0; mt < 4; ++mt) {
                    union { __hip_bfloat16 h4[4]; unsigned long long u; } pk;
                    #pragma unroll
                    for (int rg = 0; rg < 4; ++rg)
                        pk.h4[rg] = __float2bfloat16(v[mt * 4 + rg] * inv);
                    *(unsigned long long*)(wp + qtok * PS + mt * 16 + quad * 4) = pk.u;
                }
            }
        }
        LGKM_WAIT();

        // PV: oh(49x32) = P @ v ; store to OH global
        #pragma unroll
        for (int mtile = 0; mtile < 4; ++mtile) {
            v8s pa0 = lds_frag(wp, mtile * 16 + l16, PS, quad * 8, NTOK);
            v8s pa1 = lds_frag(wp, mtile * 16 + l16, PS, 32 + quad * 8, NTOK);
            #pragma unroll
            for (int nt = 0; nt < 2; ++nt) {
                v4f z = {0.f, 0.f, 0.f, 0.f};
                v4f acc = MFMA16(pa0, pb[nt][0], z, 0, 0, 0);
                acc = MFMA16(pa1, pb[nt][1], acc, 0, 0, 0);
                #pragma unroll
                for (int rg = 0; rg < 4; ++rg) {
                    int tok = mtile * 16 + quad * 4 + rg;
                    if (tok < NTOK)
                        qs[tok * 32 + nt * 16 + l16] = __float2bfloat16(acc[rg]);
                }
            }
        }
        LGKM_WAIT();   // P reads drained before next head overwrites buffers
    }
}

// ======================= phase C: projection (latency-split) ==========
// block = (window, t-quadrant); grid 8192. Sibling blocks (same window,
// different tq) keep identical bid bits 0-2 -> same XCD -> OH L2 reuse.
__global__ __launch_bounds__(256) void proj_kernel(
    const __hip_bfloat16* __restrict__ OH,   // [win][h][49][32]
    const __hip_bfloat16* __restrict__ wsP,  // (256,256) bf16
    const float* __restrict__ projB,         // (256,)
    float* __restrict__ out)                 // (32,56,56,256)
{
    const int tid = threadIdx.x, wave = tid >> 6, lane = tid & 63;
    const int quad = lane >> 4, l16 = lane & 15;
    const int bid = blockIdx.x;
    const int win = (bid & 7) | ((bid >> 5) << 3);   // bits 0-2 + bits 5-12
    const int tq  = (bid >> 3) & 3;
    const int b = win >> 6, wh = (win >> 3) & 7, wwi = win & 7;
    const int m0 = wave * 16;
    const int tokA = m0 + l16;

    // A-frags: K dim = 256 = 8 head-slots of 32 (in regs once)
    const __hip_bfloat16* ohw = OH + (size_t)win * (NH_ * NTOK * 32);
    v8s af[8];
    #pragma unroll
    for (int ks = 0; ks < 8; ++ks)
        af[ks] = (tokA < NTOK)
                   ? *(const v8s*)(ohw + ks * (NTOK * 32) + tokA * 32 + quad * 8)
                   : zero_v8s();

    // output offsets for this lane's 4 rows (window-reverse + roll(+3))
    int ooff[4];
    #pragma unroll
    for (int rg = 0; rg < 4; ++rg) {
        int row = m0 + quad * 4 + rg;
        if (row < NTOK) {
            int r = row / 7, c = row - r * 7;
            int hg = wh * 7 + r + 3; if (hg >= 56) hg -= 56;
            int wg = wwi * 7 + c + 3; if (wg >= 56) wg -= 56;
            ooff[rg] = ((b * 56 + hg) * 56 + wg) * DIM_;
        } else ooff[rg] = -1;
    }

    #pragma unroll
    for (int tt = 0; tt < 4; ++tt) {
        const int t = tq * 4 + tt;
        const __hip_bfloat16* wrow = wsP + (t * 16 + l16) * DIM_;
        v4f acc = {0.f, 0.f, 0.f, 0.f};
        #pragma unroll
        for (int ks = 0; ks < 8; ++ks) {
            v8s wf = *(const v8s*)(wrow + ks * 32 + quad * 8);
            acc = MFMA16(af[ks], wf, acc, 0, 0, 0);
        }
        float pbv = projB[t * 16 + l16];
        #pragma unroll
        for (int rg = 0; rg < 4; ++rg)
            if (ooff[rg] >= 0)
                out[ooff[rg] + t * 16 + l16] = acc[rg] + pbv;
    }
}

// ======================= fallback: round-3 fused kernel =======================
__global__ __launch_bounds__(256, 2) void swin_attn_fused(
    const float* __restrict__ x,
    const float* __restrict__ qkvB,
    const float* __restrict__ projB,
    const float* __restrict__ rbt,
    const int*   __restrict__ rpi,
    const __hip_bfloat16* __restrict__ wsQ,
    const __hip_bfloat16* __restrict__ wsP,
    const float* __restrict__ biasTab,   // class-0 rows of tabP (64x64) or null
    float*       __restrict__ out)
{
    constexpr int QKS = 40;
    constexpr int VTS = 72;
    constexpr int PS  = 72;
    constexpr int OS  = 264;
    constexpr int WVSZ = 6224;

    __shared__ alignas(16) __hip_bfloat16 s_wv[4 * WVSZ];
    __shared__ alignas(16) __hip_bfloat16 s_o[NTOK * OS];
    __shared__ int s_off[NTOK];
    __shared__ int s_reg[NTOK];

    const int tid  = threadIdx.x;
    const int wave = tid >> 6;
    const int lane = tid & 63;
    const int quad = lane >> 4;
    const int l16  = lane & 15;

    const int wid  = blockIdx.x;
    const int b    = wid >> 6;
    const int wIdx = wid & 63;
    const int wh   = wIdx >> 3;
    const int wwi  = wIdx & 7;

    if (tid < NTOK) {
        int r = tid / 7, c = tid - r * 7;
        int hs = wh * 7 + r, ws = wwi * 7 + c;
        int hg = hs + 3; if (hg >= 56) hg -= 56;
        int wg = ws + 3; if (wg >= 56) wg -= 56;
        s_off[tid] = ((b * 56 + hg) * 56 + wg) * DIM_;
        int rh = (hs < 49) ? 0 : ((hs < 53) ? 1 : 2);
        int rw = (ws < 49) ? 0 : ((ws < 53) ? 1 : 2);
        s_reg[tid] = rh * 3 + rw;
    }

    __hip_bfloat16* wq  = s_wv + wave * WVSZ;
    __hip_bfloat16* wk  = wq + NTOK * QKS;
    __hip_bfloat16* wvt = wq + 2 * NTOK * QKS;
    __hip_bfloat16* wp  = wq;

    for (int i = lane; i < 32 * 15; i += 64) {
        int f = i / 15, kk = 49 + (i % 15);
        wvt[f * VTS + kk] = __float2bfloat16(0.0f);
    }
    __syncthreads();

    const float qscale = 0.17677669529663687f;

    for (int hp = 0; hp < 2; ++hp) {
        const int h = wave * 2 + hp;
        LGKM_WAIT();

        for (int mh = 0; mh < 2; ++mh) {
            const int mbase = mh * 32;
            v8s at[2][8];
            #pragma unroll
            for (int sub = 0; sub < 2; ++sub) {
                int tok = mbase + sub * 16 + l16;
                const float* xr = (tok < NTOK) ? (x + s_off[tok]) : nullptr;
                #pragma unroll
                for (int ks = 0; ks < 8; ++ks)
                    at[sub][ks] = xr ? cvt8(xr + ks * 32 + quad * 8) : zero_v8s();
            }
            #pragma unroll
            for (int t = 0; t < 6; ++t) {
                int mat = t >> 1, ntile = t & 1;
                int nout = mat * 256 + h * 32 + ntile * 16 + l16;
                const __hip_bfloat16* wrow = wsQ + nout * DIM_;
                v4f a0 = {0.f, 0.f, 0.f, 0.f}, a1 = {0.f, 0.f, 0.f, 0.f};
                #pragma unroll
                for (int ks = 0; ks < 8; ++ks) {
                    v8s bfr = *(const v8s*)(wrow + ks * 32 + quad * 8);
                    a0 = MFMA16(at[0][ks], bfr, a0, 0, 0, 0);
                    a1 = MFMA16(at[1][ks], bfr, a1, 0, 0, 0);
                }
                float bias  = qkvB[nout];
                float scale = (mat == 0) ? qscale : 1.0f;
                #pragma unroll
                for (int sub = 0; sub < 2; ++sub) {
                    v4f acc = sub ? a1 : a0;
                    #pragma unroll
                    for (int rg = 0; rg < 4; ++rg) {
                        int row = mbase + sub * 16 + quad * 4 + rg;
                        if (row < NTOK) {
                            float val = (acc[rg] + bias) * scale;
                            int col = ntile * 16 + l16;
                            __hip_bfloat16 bv = __float2bfloat16(val);
                            if (mat == 0)      wq[row * QKS + col] = bv;
                            else if (mat == 1) wk[row * QKS + col] = bv;
                            else               wvt[col * VTS + row] = bv;
                        }
                    }
                }
            }
        }
        LGKM_WAIT();

        v8s qa[4], kb[4];
        #pragma unroll
        for (int i = 0; i < 4; ++i) {
            qa[i] = lds_frag(wq, i * 16 + l16, QKS, quad * 8, NTOK);
            kb[i] = lds_frag(wk, i * 16 + l16, QKS, quad * 8, NTOK);
        }
        int regc[4];
        #pragma unroll
        for (int nt = 0; nt < 4; ++nt) {
            int col = nt * 16 + l16;
            regc[nt] = (col < NTOK) ? s_reg[col] : -1;
        }
        LGKM_WAIT();
        const float* tabh = biasTab ? (biasTab + h * 4096) : nullptr;
        #pragma unroll
        for (int mtile = 0; mtile < 4; ++mtile) {
            v4f sa[4];
            #pragma unroll
            for (int nt = 0; nt < 4; ++nt) {
                v4f z = {0.f, 0.f, 0.f, 0.f};
                sa[nt] = MFMA16(qa[mtile], kb[nt], z, 0, 0, 0);
            }
            #pragma unroll
            for (int rg = 0; rg < 4; ++rg) {
                int row = mtile * 16 + quad * 4 + rg;
                bool rok = row < NTOK;
                int rr = rok ? s_reg[row] : -2;
                float v[4];
                float rmax = -1e30f;
                #pragma unroll
                for (int nt = 0; nt < 4; ++nt) {
                    int col = nt * 16 + l16;
                    float s = -1e30f;
                    if (rok && col < NTOK) {
                        float bv = tabh ? tabh[row * 64 + col]
                                        : rbt[rpi[row * 49 + col] * NH_ + h];
                        s = sa[nt][rg] + bv;
                        if (rr != regc[nt]) s -= 100.0f;
                    }
                    v[nt] = s;
                    rmax = fmaxf(rmax, s);
                }
                #pragma unroll
                for (int mm = 8; mm >= 1; mm >>= 1)
                    rmax = fmaxf(rmax, __shfl_xor(rmax, mm, 64));
                float rsum = 0.f;
                #pragma unroll
                for (int nt = 0; nt < 4; ++nt) {
                    float e = (v[nt] <= -1e29f) ? 0.f : __expf(v[nt] - rmax);
                    v[nt] = e;
                    rsum += e;
                }
                #pragma unroll
                for (int mm = 8; mm >= 1; mm >>= 1)
                    rsum += __shfl_xor(rsum, mm, 64);
                if (rok) {
                    float inv = 1.0f / rsum;
                    #pragma unroll
                    for (int nt = 0; nt < 4; ++nt)
                        wp[row * PS + nt * 16 + l16] = __float2bfloat16(v[nt] * inv);
                }
            }
        }
        LGKM_WAIT();

        v8s pb[2][2];
        #pragma unroll
        for (int nt = 0; nt < 2; ++nt)
            #pragma unroll
            for (int ks = 0; ks < 2; ++ks)
                pb[nt][ks] = *(const v8s*)(wvt + (nt * 16 + l16) * VTS + ks * 32 + quad * 8);
        #pragma unroll
        for (int mtile = 0; mtile < 4; ++mtile) {
            v8s pa0 = lds_frag(wp, mtile * 16 + l16, PS, quad * 8, NTOK);
            v8s pa1 = lds_frag(wp, mtile * 16 + l16, PS, 32 + quad * 8, NTOK);
            #pragma unroll
            for (int nt = 0; nt < 2; ++nt) {
                v4f z = {0.f, 0.f, 0.f, 0.f};
                v4f acc = MFMA16(pa0, pb[nt][0], z, 0, 0, 0);
                acc = MFMA16(pa1, pb[nt][1], acc, 0, 0, 0);
                #pragma unroll
                for (int rg = 0; rg < 4; ++rg) {
                    int row = mtile * 16 + quad * 4 + rg;
                    if (row < NTOK)
                        s_o[row * OS + h * 32 + nt * 16 + l16] = __float2bfloat16(acc[rg]);
                }
            }
        }
    }
    __syncthreads();

    {
        int m0 = wave * 16;
        v8s af[8];
        #pragma unroll
        for (int ks = 0; ks < 8; ++ks)
            af[ks] = lds_frag(s_o, m0 + l16, OS, ks * 32 + quad * 8, NTOK);
        #pragma unroll
        for (int t = 0; t < 16; ++t) {
            const __hip_bfloat16* wrow = wsP + (t * 16 + l16) * DIM_;
            v4f acc = {0.f, 0.f, 0.f, 0.f};
            #pragma unroll
            for (int ks = 0; ks < 8; ++ks) {
                v8s bfr = *(const v8s*)(wrow + ks * 32 + quad * 8);
                acc = MFMA16(af[ks], bfr, acc, 0, 0, 0);
            }
            float pbv = projB[t * 16 + l16];
            #pragma unroll
            for (int rg = 0; rg < 4; ++rg) {
                int row = m0 + quad * 4 + rg;
                if (row < NTOK)
                    out[s_off[row] + t * 16 + l16] = acc[rg] + pbv;
            }
        }
    }
}

extern "C" void kernel_launch(void* const* d_in, const int* in_sizes, int n_in,
                              void* d_out, int out_size, void* d_ws, size_t ws_size,
                              hipStream_t stream) {
    const float* x     = (const float*)d_in[0];
    const float* qkvW  = (const float*)d_in[1];
    const float* qkvB  = (const float*)d_in[2];
    const float* projW = (const float*)d_in[3];
    const float* projB = (const float*)d_in[4];
    const float* rbt   = (const float*)d_in[5];
    const int*   rpi   = (const int*)d_in[6];
    float* o = (float*)d_out;

    __hip_bfloat16* wsQ = (__hip_bfloat16*)d_ws;
    __hip_bfloat16* wsP = (__hip_bfloat16*)((char*)d_ws + WSP_B);
    float* tabP         = (float*)((char*)d_ws + TAB_B);
    __hip_bfloat16* OH  = (__hip_bfloat16*)((char*)d_ws + Q_B);

    const int prepBlocks = (NQKV + NPRJ + NTABP + 255) / 256;

    if (ws_size >= NEED_BIG) {
        prep_kernel<<<prepBlocks, 256, 0, stream>>>(qkvW, projW, rbt, rpi,
                                                    wsQ, wsP, tabP, 1);
        qkvattn_kernel<<<2048, 256, 0, stream>>>(x, qkvB, wsQ, tabP, OH);
        proj_kernel<<<8192, 256, 0, stream>>>(OH, wsP, projB, o);
    } else {
        int doTab = (ws_size >= NEED_TAB) ? 1 : 0;
        prep_kernel<<<prepBlocks, 256, 0, stream>>>(qkvW, projW, rbt, rpi,
                                                    wsQ, wsP, tabP, doTab);
        swin_attn_fused<<<2048, 256, 0, stream>>>(x, qkvB, projB, rbt, rpi,
                                                  wsQ, wsP, doTab ? tabP : nullptr, o);
    }
}

// Round 6
// 437.221 us; speedup vs baseline: 1.2216x; 1.0681x over previous
//
#include <hip/hip_runtime.h>
#include <hip/hip_bf16.h>

// Shifted-window attention (Swin), B=32 H=W=56 C=256 NH=8 hd=32 WS=7 SHIFT=3.
// fp32 in/out; bf16 MFMA compute.
//
// Main path: 2 kernels
//   prep: weights fp32->bf16; padded bias+mask table tabP[4][8][64][64] fp32
//         (rows/cols >=49 filled with -1e30 -> masking is free in attn)
//   mega: FULLY FUSED per-window QKV + attention + projection.
//         One block per window, 4 waves, each wave owns 2 heads.
//         QKV (MFMA32) -> wave-private LDS; S^T=K·Q^T softmax (in-lane reduce
//         + 2 shuffles, padded tab v4f loads); PV output held in REGISTERS;
//         after both heads, s_x is dead and is reused as s_o[49][264] for the
//         projection epilogue (oh @ projW^T + bias, fp32 scatter w/ reverse
//         shift). No OH global roundtrip, no third kernel.
// Fallback (small ws): previous fused kernel (tab indexing 64x64).

#define NTOK 49
#define DIM_ 256
#define NH_  8
#define NQKV 196608          // 768*256
#define NPRJ 65536           // 256*256
#define NTABP 131072         // 4*8*64*64 padded table

// ---- workspace layout (bytes) ----
#define WSP_B  393216ull                       // after wsQ (NQKV*2)
#define TAB_B  524288ull                       // after wsP (NPRJ*2)
#define NEED_TAB (TAB_B + (unsigned long long)NTABP * 4)   // 1,048,576

typedef short v8s __attribute__((ext_vector_type(8)));
typedef float v4f __attribute__((ext_vector_type(4)));
typedef float v16f __attribute__((ext_vector_type(16)));

#define MFMA16 __builtin_amdgcn_mfma_f32_16x16x32_bf16
#define MFMA32 __builtin_amdgcn_mfma_f32_32x32x16_bf16
#define LGKM_WAIT() asm volatile("s_waitcnt lgkmcnt(0)" ::: "memory")

static __device__ __forceinline__ v8s zero_v8s() {
    v8s z = {0, 0, 0, 0, 0, 0, 0, 0};
    return z;
}

static __device__ __forceinline__ v16f zero_v16f() {
    v16f z;
    #pragma unroll
    for (int i = 0; i < 16; ++i) z[i] = 0.0f;
    return z;
}

static __device__ __forceinline__ v8s lds_frag(const __hip_bfloat16* p, int row,
                                               int stride, int koff, int nrows) {
    if (row < nrows) return *(const v8s*)(p + row * stride + koff);
    return zero_v8s();
}

// 8 consecutive fp32 -> 8 bf16 fragment (32B-aligned source)
static __device__ __forceinline__ v8s cvt8(const float* p) {
    v4f a = *(const v4f*)p;
    v4f b = *(const v4f*)(p + 4);
    union { v8s v; __hip_bfloat16 h[8]; } r;
    r.h[0] = __float2bfloat16(a[0]); r.h[1] = __float2bfloat16(a[1]);
    r.h[2] = __float2bfloat16(a[2]); r.h[3] = __float2bfloat16(a[3]);
    r.h[4] = __float2bfloat16(b[0]); r.h[5] = __float2bfloat16(b[1]);
    r.h[6] = __float2bfloat16(b[2]); r.h[7] = __float2bfloat16(b[3]);
    return r.v;
}

// ======================= prep =======================
__global__ __launch_bounds__(256) void prep_kernel(
    const float* __restrict__ qkvW, const float* __restrict__ projW,
    const float* __restrict__ rbt, const int* __restrict__ rpi,
    __hip_bfloat16* __restrict__ wsQ, __hip_bfloat16* __restrict__ wsP,
    float* __restrict__ tabP, int doTab)
{
    int i = blockIdx.x * 256 + threadIdx.x;
    if (i < NQKV) { wsQ[i] = __float2bfloat16(qkvW[i]); return; }
    int j = i - NQKV;
    if (j < NPRJ) { wsP[j] = __float2bfloat16(projW[j]); return; }
    int t = j - NPRJ;
    if (!doTab || t >= NTABP) return;
    int cls = t >> 15;          // /(8*64*64)
    int rem = t & 32767;
    int h = rem >> 12;          // /4096
    int p = rem & 4095;
    int row = p >> 6, col = p & 63;
    float val = -1e30f;
    if (row < NTOK && col < NTOK) {
        // region id: nonzero only on edge windows (cls bit0=h-edge, bit1=w-edge)
        int rh = (cls & 1) ? (((row / 7) < 4) ? 1 : 2) : 0;
        int rw = (cls & 2) ? (((row % 7) < 4) ? 1 : 2) : 0;
        int ch = (cls & 1) ? (((col / 7) < 4) ? 1 : 2) : 0;
        int cw = (cls & 2) ? (((col % 7) < 4) ? 1 : 2) : 0;
        float mask = ((rh * 3 + rw) != (ch * 3 + cw)) ? -100.0f : 0.0f;
        val = rbt[rpi[row * 49 + col] * NH_ + h] + mask;
    }
    tabP[t] = val;
}

// ======================= fused QKV + attention + projection ==========
__global__ __launch_bounds__(256) void swin_mega_kernel(
    const float* __restrict__ x,       // (32,56,56,256)
    const float* __restrict__ qkvB,    // (768,)
    const __hip_bfloat16* __restrict__ wsQ,  // (768,256) bf16
    const __hip_bfloat16* __restrict__ wsP,  // (256,256) bf16
    const float* __restrict__ projB,   // (256,)
    const float* __restrict__ tabP,    // [4][8][64][64] bias+mask, padded
    float* __restrict__ out)           // (32,56,56,256)
{
    constexpr int SXS = 264;   // s_x/s_o row stride (el)
    constexpr int QKS = 40;    // wq/wk row stride (el)
    constexpr int VTS = 72;    // wvt row stride (el)
    constexpr int PS  = 72;    // P row stride (el); P overlays wq+wk
    constexpr int WVSZ = 2 * NTOK * QKS + 32 * VTS;   // 6224 el

    __shared__ alignas(16) __hip_bfloat16 s_x[NTOK * SXS];    // 25,872 B; reused as s_o
    __shared__ alignas(16) __hip_bfloat16 s_wv[4 * WVSZ];     // 49,792 B

    const int tid = threadIdx.x, wave = tid >> 6, lane = tid & 63;
    const int quad = lane >> 4, l16 = lane & 15;
    const int l32 = lane & 31, half = lane >> 5;
    const int win = blockIdx.x;
    const int b = win >> 6, wh = (win >> 3) & 7, wwi = win & 7;
    const int cls = ((wh == 7) ? 1 : 0) | ((wwi == 7) ? 2 : 0);

    __hip_bfloat16* wq  = s_wv + wave * WVSZ;
    __hip_bfloat16* wk  = wq + NTOK * QKS;
    __hip_bfloat16* wvt = wq + 2 * NTOK * QKS;
    __hip_bfloat16* wp  = wq;                     // P overlays q+k (dead then)

    // zero wvt pad cols 49..55 (per wave; persists across both heads)
    for (int i = lane; i < 32 * 7; i += 64)
        wvt[(i / 7) * VTS + 49 + (i % 7)] = __float2bfloat16(0.0f);

    // stage window x -> bf16 LDS (shifted gather), cooperative, packed 8B stores
    for (int i = tid; i < NTOK * 64; i += 256) {
        int tok = i >> 6, f4 = (i & 63) * 4;
        int r = tok / 7, c = tok - r * 7;
        int hg = wh * 7 + r + 3; if (hg >= 56) hg -= 56;
        int wg = wwi * 7 + c + 3; if (wg >= 56) wg -= 56;
        float4 v = *(const float4*)(x + ((b * 56 + hg) * 56 + wg) * DIM_ + f4);
        union { ushort4 u4; __hip_bfloat16 h[4]; } pkst;
        pkst.h[0] = __float2bfloat16(v.x);
        pkst.h[1] = __float2bfloat16(v.y);
        pkst.h[2] = __float2bfloat16(v.z);
        pkst.h[3] = __float2bfloat16(v.w);
        *(ushort4*)(s_x + tok * SXS + f4) = pkst.u4;   // 8B aligned (SXS mult of 8)
    }
    __syncthreads();

    const float qscale = 0.17677669529663687f;  // 1/sqrt(32)
    // clamped second-tile row (tokens 32..63 -> clamp >=49 to 0; results masked)
    const int r1 = (32 + l32 < NTOK) ? (32 + l32) : 0;
    const __hip_bfloat16* arow0 = s_x + l32 * SXS + half * 8;
    const __hip_bfloat16* arow1 = s_x + r1 * SXS + half * 8;

    // PV outputs for both heads, kept in registers (all indices static).
    v4f ohacc[2][4][2];

    #pragma unroll
    for (int hp = 0; hp < 2; ++hp) {
        const int h = wave * 2 + hp;

        // ---------- QKV for head h: 3 col-tiles (q, k, v) ----------
        #pragma unroll
        for (int m = 0; m < 3; ++m) {
            const int nb = m * 256 + h * 32;
            const __hip_bfloat16* wrow = wsQ + (nb + l32) * DIM_ + half * 8;
            v16f acc0 = zero_v16f(), acc1 = zero_v16f();

            if (m < 2) {
                // C rows = tokens, C cols = out features
                #pragma unroll
                for (int kh = 0; kh < 2; ++kh) {
                    v8s wf[8];
                    #pragma unroll
                    for (int k = 0; k < 8; ++k)
                        wf[k] = *(const v8s*)(wrow + kh * 128 + k * 16);
                    #pragma unroll
                    for (int k = 0; k < 8; ++k) {
                        v8s a0 = *(const v8s*)(arow0 + kh * 128 + k * 16);
                        v8s a1 = *(const v8s*)(arow1 + kh * 128 + k * 16);
                        acc0 = MFMA32(a0, wf[k], acc0, 0, 0, 0);
                        acc1 = MFMA32(a1, wf[k], acc1, 0, 0, 0);
                    }
                }
                float bias = qkvB[nb + l32];
                float sc = (m == 0) ? qscale : 1.0f;
                __hip_bfloat16* dst = (m == 0) ? wq : wk;
                #pragma unroll
                for (int rg = 0; rg < 16; ++rg) {
                    int rowoff = (rg & 3) + 8 * (rg >> 2) + 4 * half;   // 0..31
                    dst[rowoff * QKS + l32] =
                        __float2bfloat16((acc0[rg] + bias) * sc);
                    int tok1 = 32 + rowoff;
                    if (tok1 < NTOK)
                        dst[tok1 * QKS + l32] =
                            __float2bfloat16((acc1[rg] + bias) * sc);
                }
            } else {
                // swapped operands: C rows = features, C cols = tokens (VT layout)
                #pragma unroll
                for (int kh = 0; kh < 2; ++kh) {
                    v8s wf[8];
                    #pragma unroll
                    for (int k = 0; k < 8; ++k)
                        wf[k] = *(const v8s*)(wrow + kh * 128 + k * 16);
                    #pragma unroll
                    for (int k = 0; k < 8; ++k) {
                        v8s b0 = *(const v8s*)(arow0 + kh * 128 + k * 16);
                        v8s b1 = *(const v8s*)(arow1 + kh * 128 + k * 16);
                        acc0 = MFMA32(wf[k], b0, acc0, 0, 0, 0);
                        acc1 = MFMA32(wf[k], b1, acc1, 0, 0, 0);
                    }
                }
                const int tok1 = 32 + l32;           // masked >= 49
                #pragma unroll
                for (int rg = 0; rg < 16; ++rg) {
                    int feat = (rg & 3) + 8 * (rg >> 2) + 4 * half;     // 0..31
                    float bias = qkvB[nb + feat];
                    wvt[feat * VTS + l32] = __float2bfloat16(acc0[rg] + bias);
                    if (tok1 < NTOK)
                        wvt[feat * VTS + tok1] = __float2bfloat16(acc1[rg] + bias);
                }
            }
        }
        LGKM_WAIT();   // wave-local q/k/vt writes drained before reads

        // ---------- attention head h (wave-local) ----------
        const float* tabh = tabP + (cls * NH_ + h) * 4096;   // [64][64]

        v8s qa[4], kb[4];
        #pragma unroll
        for (int mt = 0; mt < 4; ++mt) {
            qa[mt] = lds_frag(wq, mt * 16 + l16, QKS, quad * 8, NTOK);
            kb[mt] = lds_frag(wk, mt * 16 + l16, QKS, quad * 8, NTOK);
        }
        v8s pb[2][2];
        #pragma unroll
        for (int nt = 0; nt < 2; ++nt) {
            const __hip_bfloat16* vr = wvt + (nt * 16 + l16) * VTS;
            pb[nt][0] = *(const v8s*)(vr + quad * 8);
            pb[nt][1] = (quad == 3) ? zero_v8s() : *(const v8s*)(vr + 32 + quad * 8);
        }
        LGKM_WAIT();   // qa/kb/pb in regs before wp overlays wq/wk

        // S^T = K·Q^T: lane owns q-row (ntq*16+l16), k-values in regs.
        // softmax = in-lane reduce + 2 shuffles; P packed to LDS as b64.
        #pragma unroll
        for (int ntq = 0; ntq < 4; ++ntq) {
            const int qtok = ntq * 16 + l16;
            // prefetch bias+mask: 4 aligned v4f (padded rows make this safe)
            v4f tv[4];
            #pragma unroll
            for (int mt = 0; mt < 4; ++mt)
                tv[mt] = *(const v4f*)(tabh + qtok * 64 + mt * 16 + quad * 4);
            v4f st[4];
            #pragma unroll
            for (int mt = 0; mt < 4; ++mt) {
                v4f z = {0.f, 0.f, 0.f, 0.f};
                st[mt] = MFMA16(kb[mt], qa[ntq], z, 0, 0, 0);
            }
            float v[16];
            float rmax = -1e30f;
            #pragma unroll
            for (int mt = 0; mt < 4; ++mt)
                #pragma unroll
                for (int rg = 0; rg < 4; ++rg) {
                    float s = st[mt][rg] + tv[mt][rg];
                    v[mt * 4 + rg] = s;
                    rmax = fmaxf(rmax, s);
                }
            // lanes ^16/^32 share the same q-token (col=lane&15)
            rmax = fmaxf(rmax, __shfl_xor(rmax, 16, 64));
            rmax = fmaxf(rmax, __shfl_xor(rmax, 32, 64));
            float rsum = 0.f;
            #pragma unroll
            for (int i = 0; i < 16; ++i) {
                float e = (v[i] <= -1e29f) ? 0.f : __expf(v[i] - rmax);
                v[i] = e;
                rsum += e;
            }
            rsum += __shfl_xor(rsum, 16, 64);
            rsum += __shfl_xor(rsum, 32, 64);
            if (qtok < NTOK) {
                float inv = 1.0f / rsum;
                #pragma unroll
                for (int mt = 0; mt < 4; ++mt) {
                    union { __hip_bfloat16 h4[4]; unsigned long long u; } pk;
                    #pragma unroll
                    for (int rg = 0; rg < 4; ++rg)
                        pk.h4[rg] = __float2bfloat16(v[mt * 4 + rg] * inv);
                    *(unsigned long long*)(wp + qtok * PS + mt * 16 + quad * 4) = pk.u;
                }
            }
        }
        LGKM_WAIT();

        // PV: oh(49x32) = P @ v ; keep in registers (static indices)
        #pragma unroll
        for (int mtile = 0; mtile < 4; ++mtile) {
            v8s pa0 = lds_frag(wp, mtile * 16 + l16, PS, quad * 8, NTOK);
            v8s pa1 = lds_frag(wp, mtile * 16 + l16, PS, 32 + quad * 8, NTOK);
            #pragma unroll
            for (int nt = 0; nt < 2; ++nt) {
                v4f z = {0.f, 0.f, 0.f, 0.f};
                v4f acc = MFMA16(pa0, pb[nt][0], z, 0, 0, 0);
                acc = MFMA16(pa1, pb[nt][1], acc, 0, 0, 0);
                ohacc[hp][mtile][nt] = acc;
            }
        }
        LGKM_WAIT();   // P reads drained before next head overwrites buffers
    }

    // all waves done with s_x (QKV) and their private LDS -> reuse s_x as s_o
    __syncthreads();
    __hip_bfloat16* s_o = s_x;   // [49][264]; head h at cols h*32..h*32+31

    #pragma unroll
    for (int hp = 0; hp < 2; ++hp) {
        const int h = wave * 2 + hp;
        #pragma unroll
        for (int mtile = 0; mtile < 4; ++mtile)
            #pragma unroll
            for (int nt = 0; nt < 2; ++nt)
                #pragma unroll
                for (int rg = 0; rg < 4; ++rg) {
                    int tok = mtile * 16 + quad * 4 + rg;
                    if (tok < NTOK)
                        s_o[tok * SXS + h * 32 + nt * 16 + l16] =
                            __float2bfloat16(ohacc[hp][mtile][nt][rg]);
                }
    }
    __syncthreads();

    // ---------- projection epilogue: out = oh @ projW^T + bias ----------
    {
        const int m0 = wave * 16;
        v8s af[8];
        #pragma unroll
        for (int ks = 0; ks < 8; ++ks)
            af[ks] = lds_frag(s_o, m0 + l16, SXS, ks * 32 + quad * 8, NTOK);

        // output offsets for this lane's 4 rows (window-reverse + roll(+3))
        int ooff[4];
        #pragma unroll
        for (int rg = 0; rg < 4; ++rg) {
            int row = m0 + quad * 4 + rg;
            if (row < NTOK) {
                int r = row / 7, c = row - r * 7;
                int hg = wh * 7 + r + 3; if (hg >= 56) hg -= 56;
                int wg = wwi * 7 + c + 3; if (wg >= 56) wg -= 56;
                ooff[rg] = ((b * 56 + hg) * 56 + wg) * DIM_;
            } else ooff[rg] = -1;
        }
        LGKM_WAIT();

        #pragma unroll
        for (int t = 0; t < 16; ++t) {
            const __hip_bfloat16* wrow = wsP + (t * 16 + l16) * DIM_;
            v4f acc = {0.f, 0.f, 0.f, 0.f};
            #pragma unroll
            for (int ks = 0; ks < 8; ++ks) {
                v8s wf = *(const v8s*)(wrow + ks * 32 + quad * 8);
                acc = MFMA16(af[ks], wf, acc, 0, 0, 0);
            }
            float pbv = projB[t * 16 + l16];
            #pragma unroll
            for (int rg = 0; rg < 4; ++rg)
                if (ooff[rg] >= 0)
                    out[ooff[rg] + t * 16 + l16] = acc[rg] + pbv;
        }
    }
}

// ======================= fallback: previous fused kernel ==================
__global__ __launch_bounds__(256, 2) void swin_attn_fused(
    const float* __restrict__ x,
    const float* __restrict__ qkvB,
    const float* __restrict__ projB,
    const float* __restrict__ rbt,
    const int*   __restrict__ rpi,
    const __hip_bfloat16* __restrict__ wsQ,
    const __hip_bfloat16* __restrict__ wsP,
    const float* __restrict__ biasTab,   // class-0 rows of tabP (64x64) or null
    float*       __restrict__ out)
{
    constexpr int QKS = 40;
    constexpr int VTS = 72;
    constexpr int PS  = 72;
    constexpr int OS  = 264;
    constexpr int WVSZ = 6224;

    __shared__ alignas(16) __hip_bfloat16 s_wv[4 * WVSZ];
    __shared__ alignas(16) __hip_bfloat16 s_o[NTOK * OS];
    __shared__ int s_off[NTOK];
    __shared__ int s_reg[NTOK];

    const int tid  = threadIdx.x;
    const int wave = tid >> 6;
    const int lane = tid & 63;
    const int quad = lane >> 4;
    const int l16  = lane & 15;

    const int wid  = blockIdx.x;
    const int b    = wid >> 6;
    const int wIdx = wid & 63;
    const int wh   = wIdx >> 3;
    const int wwi  = wIdx & 7;

    if (tid < NTOK) {
        int r = tid / 7, c = tid - r * 7;
        int hs = wh * 7 + r, ws = wwi * 7 + c;
        int hg = hs + 3; if (hg >= 56) hg -= 56;
        int wg = ws + 3; if (wg >= 56) wg -= 56;
        s_off[tid] = ((b * 56 + hg) * 56 + wg) * DIM_;
        int rh = (hs < 49) ? 0 : ((hs < 53) ? 1 : 2);
        int rw = (ws < 49) ? 0 : ((ws < 53) ? 1 : 2);
        s_reg[tid] = rh * 3 + rw;
    }

    __hip_bfloat16* wq  = s_wv + wave * WVSZ;
    __hip_bfloat16* wk  = wq + NTOK * QKS;
    __hip_bfloat16* wvt = wq + 2 * NTOK * QKS;
    __hip_bfloat16* wp  = wq;

    for (int i = lane; i < 32 * 15; i += 64) {
        int f = i / 15, kk = 49 + (i % 15);
        wvt[f * VTS + kk] = __float2bfloat16(0.0f);
    }
    __syncthreads();

    const float qscale = 0.17677669529663687f;

    for (int hp = 0; hp < 2; ++hp) {
        const int h = wave * 2 + hp;
        LGKM_WAIT();

        for (int mh = 0; mh < 2; ++mh) {
            const int mbase = mh * 32;
            v8s at[2][8];
            #pragma unroll
            for (int sub = 0; sub < 2; ++sub) {
                int tok = mbase + sub * 16 + l16;
                const float* xr = (tok < NTOK) ? (x + s_off[tok]) : nullptr;
                #pragma unroll
                for (int ks = 0; ks < 8; ++ks)
                    at[sub][ks] = xr ? cvt8(xr + ks * 32 + quad * 8) : zero_v8s();
            }
            #pragma unroll
            for (int t = 0; t < 6; ++t) {
                int mat = t >> 1, ntile = t & 1;
                int nout = mat * 256 + h * 32 + ntile * 16 + l16;
                const __hip_bfloat16* wrow = wsQ + nout * DIM_;
                v4f a0 = {0.f, 0.f, 0.f, 0.f}, a1 = {0.f, 0.f, 0.f, 0.f};
                #pragma unroll
                for (int ks = 0; ks < 8; ++ks) {
                    v8s bfr = *(const v8s*)(wrow + ks * 32 + quad * 8);
                    a0 = MFMA16(at[0][ks], bfr, a0, 0, 0, 0);
                    a1 = MFMA16(at[1][ks], bfr, a1, 0, 0, 0);
                }
                float bias  = qkvB[nout];
                float scale = (mat == 0) ? qscale : 1.0f;
                #pragma unroll
                for (int sub = 0; sub < 2; ++sub) {
                    v4f acc = sub ? a1 : a0;
                    #pragma unroll
                    for (int rg = 0; rg < 4; ++rg) {
                        int row = mbase + sub * 16 + quad * 4 + rg;
                        if (row < NTOK) {
                            float val = (acc[rg] + bias) * scale;
                            int col = ntile * 16 + l16;
                            __hip_bfloat16 bv = __float2bfloat16(val);
                            if (mat == 0)      wq[row * QKS + col] = bv;
                            else if (mat == 1) wk[row * QKS + col] = bv;
                            else               wvt[col * VTS + row] = bv;
                        }
                    }
                }
            }
        }
        LGKM_WAIT();

        v8s qa[4], kb[4];
        #pragma unroll
        for (int i = 0; i < 4; ++i) {
            qa[i] = lds_frag(wq, i * 16 + l16, QKS, quad * 8, NTOK);
            kb[i] = lds_frag(wk, i * 16 + l16, QKS, quad * 8, NTOK);
        }
        int regc[4];
        #pragma unroll
        for (int nt = 0; nt < 4; ++nt) {
            int col = nt * 16 + l16;
            regc[nt] = (col < NTOK) ? s_reg[col] : -1;
        }
        LGKM_WAIT();
        const float* tabh = biasTab ? (biasTab + h * 4096) : nullptr;
        #pragma unroll
        for (int mtile = 0; mtile < 4; ++mtile) {
            v4f sa[4];
            #pragma unroll
            for (int nt = 0; nt < 4; ++nt) {
                v4f z = {0.f, 0.f, 0.f, 0.f};
                sa[nt] = MFMA16(qa[mtile], kb[nt], z, 0, 0, 0);
            }
            #pragma unroll
            for (int rg = 0; rg < 4; ++rg) {
                int row = mtile * 16 + quad * 4 + rg;
                bool rok = row < NTOK;
                int rr = rok ? s_reg[row] : -2;
                float v[4];
                float rmax = -1e30f;
                #pragma unroll
                for (int nt = 0; nt < 4; ++nt) {
                    int col = nt * 16 + l16;
                    float s = -1e30f;
                    if (rok && col < NTOK) {
                        float bv = tabh ? tabh[row * 64 + col]
                                        : rbt[rpi[row * 49 + col] * NH_ + h];
                        s = sa[nt][rg] + bv;
                        if (rr != regc[nt]) s -= 100.0f;
                    }
                    v[nt] = s;
                    rmax = fmaxf(rmax, s);
                }
                #pragma unroll
                for (int mm = 8; mm >= 1; mm >>= 1)
                    rmax = fmaxf(rmax, __shfl_xor(rmax, mm, 64));
                float rsum = 0.f;
                #pragma unroll
                for (int nt = 0; nt < 4; ++nt) {
                    float e = (v[nt] <= -1e29f) ? 0.f : __expf(v[nt] - rmax);
                    v[nt] = e;
                    rsum += e;
                }
                #pragma unroll
                for (int mm = 8; mm >= 1; mm >>= 1)
                    rsum += __shfl_xor(rsum, mm, 64);
                if (rok) {
                    float inv = 1.0f / rsum;
                    #pragma unroll
                    for (int nt = 0; nt < 4; ++nt)
                        wp[row * PS + nt * 16 + l16] = __float2bfloat16(v[nt] * inv);
                }
            }
        }
        LGKM_WAIT();

        v8s pb[2][2];
        #pragma unroll
        for (int nt = 0; nt < 2; ++nt)
            #pragma unroll
            for (int ks = 0; ks < 2; ++ks)
                pb[nt][ks] = *(const v8s*)(wvt + (nt * 16 + l16) * VTS + ks * 32 + quad * 8);
        #pragma unroll
        for (int mtile = 0; mtile < 4; ++mtile) {
            v8s pa0 = lds_frag(wp, mtile * 16 + l16, PS, quad * 8, NTOK);
            v8s pa1 = lds_frag(wp, mtile * 16 + l16, PS, 32 + quad * 8, NTOK);
            #pragma unroll
            for (int nt = 0; nt < 2; ++nt) {
                v4f z = {0.f, 0.f, 0.f, 0.f};
                v4f acc = MFMA16(pa0, pb[nt][0], z, 0, 0, 0);
                acc = MFMA16(pa1, pb[nt][1], acc, 0, 0, 0);
                #pragma unroll
                for (int rg = 0; rg < 4; ++rg) {
                    int row = mtile * 16 + quad * 4 + rg;
                    if (row < NTOK)
                        s_o[row * OS + h * 32 + nt * 16 + l16] = __float2bfloat16(acc[rg]);
                }
            }
        }
    }
    __syncthreads();

    {
        int m0 = wave * 16;
        v8s af[8];
        #pragma unroll
        for (int ks = 0; ks < 8; ++ks)
            af[ks] = lds_frag(s_o, m0 + l16, OS, ks * 32 + quad * 8, NTOK);
        #pragma unroll
        for (int t = 0; t < 16; ++t) {
            const __hip_bfloat16* wrow = wsP + (t * 16 + l16) * DIM_;
            v4f acc = {0.f, 0.f, 0.f, 0.f};
            #pragma unroll
            for (int ks = 0; ks < 8; ++ks) {
                v8s bfr = *(const v8s*)(wrow + ks * 32 + quad * 8);
                acc = MFMA16(af[ks], bfr, acc, 0, 0, 0);
            }
            float pbv = projB[t * 16 + l16];
            #pragma unroll
            for (int rg = 0; rg < 4; ++rg) {
                int row = m0 + quad * 4 + rg;
                if (row < NTOK)
                    out[s_off[row] + t * 16 + l16] = acc[rg] + pbv;
            }
        }
    }
}

extern "C" void kernel_launch(void* const* d_in, const int* in_sizes, int n_in,
                              void* d_out, int out_size, void* d_ws, size_t ws_size,
                              hipStream_t stream) {
    const float* x     = (const float*)d_in[0];
    const float* qkvW  = (const float*)d_in[1];
    const float* qkvB  = (const float*)d_in[2];
    const float* projW = (const float*)d_in[3];
    const float* projB = (const float*)d_in[4];
    const float* rbt   = (const float*)d_in[5];
    const int*   rpi   = (const int*)d_in[6];
    float* o = (float*)d_out;

    __hip_bfloat16* wsQ = (__hip_bfloat16*)d_ws;
    __hip_bfloat16* wsP = (__hip_bfloat16*)((char*)d_ws + WSP_B);
    float* tabP         = (float*)((char*)d_ws + TAB_B);

    const int prepBlocks = (NQKV + NPRJ + NTABP + 255) / 256;

    if (ws_size >= NEED_TAB) {
        prep_kernel<<<prepBlocks, 256, 0, stream>>>(qkvW, projW, rbt, rpi,
                                                    wsQ, wsP, tabP, 1);
        swin_mega_kernel<<<2048, 256, 0, stream>>>(x, qkvB, wsQ, wsP, projB,
                                                   tabP, o);
    } else {
        prep_kernel<<<prepBlocks, 256, 0, stream>>>(qkvW, projW, rbt, rpi,
                                                    wsQ, wsP, tabP, 0);
        swin_attn_fused<<<2048, 256, 0, stream>>>(x, qkvB, projB, rbt, rpi,
                                                  wsQ, wsP, nullptr, o);
    }
}

// Round 8
// 408.414 us; speedup vs baseline: 1.3078x; 1.0705x over previous
//
#include <hip/hip_runtime.h>
#include <hip/hip_bf16.h>

// Shifted-window attention (Swin), B=32 H=W=56 C=256 NH=8 hd=32 WS=7 SHIFT=3.
// fp32 in/out; bf16 MFMA compute.
//
// Main path: 2 kernels
//   prep: weights fp32->bf16; padded bias+mask table tabP[4][8][64][64] fp32
//   mega: FULLY FUSED per-window QKV + attention + projection.
//         One block per window, 4 waves, each wave owns 2 heads.
//         LDS TIME-MULTIPLEXED: per-wave 7,056 B region reused sequentially
//         {q -> qa regs -> k -> kb regs -> vt -> pb regs -> P}, each boundary
//         fenced by s_waitcnt lgkmcnt(0) + sched_barrier(0) (rule-#18 fix:
//         the sched_barrier pins compile-time order; the asm "memory" clobber
//         alone is not sufficient against the machine scheduler).
//         Block LDS = 54,096 B -> 3 blocks/CU.
//         PV output in registers; s_x reused as s_o for the projection
//         epilogue (wave owns a t-quarter: weights hoisted once, af from LDS).
// Fallback (small ws): previous fused kernel (tab indexing 64x64).

#define NTOK 49
#define DIM_ 256
#define NH_  8
#define NQKV 196608          // 768*256
#define NPRJ 65536           // 256*256
#define NTABP 131072         // 4*8*64*64 padded table

// ---- workspace layout (bytes) ----
#define WSP_B  393216ull                       // after wsQ (NQKV*2)
#define TAB_B  524288ull                       // after wsP (NPRJ*2)
#define NEED_TAB (TAB_B + (unsigned long long)NTABP * 4)   // 1,048,576

typedef short v8s __attribute__((ext_vector_type(8)));
typedef float v4f __attribute__((ext_vector_type(4)));
typedef float v16f __attribute__((ext_vector_type(16)));

#define MFMA16 __builtin_amdgcn_mfma_f32_16x16x32_bf16
#define MFMA32 __builtin_amdgcn_mfma_f32_32x32x16_bf16
#define LGKM_WAIT() asm volatile("s_waitcnt lgkmcnt(0)" ::: "memory")
// Hardened wave-local fence: runtime wait + compile-time scheduling pin.
#define WAVE_FENCE()                                   \
    do {                                               \
        asm volatile("s_waitcnt lgkmcnt(0)" ::: "memory"); \
        __builtin_amdgcn_sched_barrier(0);             \
    } while (0)

static __device__ __forceinline__ v8s zero_v8s() {
    v8s z = {0, 0, 0, 0, 0, 0, 0, 0};
    return z;
}

static __device__ __forceinline__ v16f zero_v16f() {
    v16f z;
    #pragma unroll
    for (int i = 0; i < 16; ++i) z[i] = 0.0f;
    return z;
}

static __device__ __forceinline__ v8s lds_frag(const __hip_bfloat16* p, int row,
                                               int stride, int koff, int nrows) {
    if (row < nrows) return *(const v8s*)(p + row * stride + koff);
    return zero_v8s();
}

// 8 consecutive fp32 -> 8 bf16 fragment (32B-aligned source)
static __device__ __forceinline__ v8s cvt8(const float* p) {
    v4f a = *(const v4f*)p;
    v4f b = *(const v4f*)(p + 4);
    union { v8s v; __hip_bfloat16 h[8]; } r;
    r.h[0] = __float2bfloat16(a[0]); r.h[1] = __float2bfloat16(a[1]);
    r.h[2] = __float2bfloat16(a[2]); r.h[3] = __float2bfloat16(a[3]);
    r.h[4] = __float2bfloat16(b[0]); r.h[5] = __float2bfloat16(b[1]);
    r.h[6] = __float2bfloat16(b[2]); r.h[7] = __float2bfloat16(b[3]);
    return r.v;
}

// ======================= prep =======================
__global__ __launch_bounds__(256) void prep_kernel(
    const float* __restrict__ qkvW, const float* __restrict__ projW,
    const float* __restrict__ rbt, const int* __restrict__ rpi,
    __hip_bfloat16* __restrict__ wsQ, __hip_bfloat16* __restrict__ wsP,
    float* __restrict__ tabP, int doTab)
{
    int i = blockIdx.x * 256 + threadIdx.x;
    if (i < NQKV) { wsQ[i] = __float2bfloat16(qkvW[i]); return; }
    int j = i - NQKV;
    if (j < NPRJ) { wsP[j] = __float2bfloat16(projW[j]); return; }
    int t = j - NPRJ;
    if (!doTab || t >= NTABP) return;
    int cls = t >> 15;          // /(8*64*64)
    int rem = t & 32767;
    int h = rem >> 12;          // /4096
    int p = rem & 4095;
    int row = p >> 6, col = p & 63;
    float val = -1e30f;
    if (row < NTOK && col < NTOK) {
        // region id: nonzero only on edge windows (cls bit0=h-edge, bit1=w-edge)
        int rh = (cls & 1) ? (((row / 7) < 4) ? 1 : 2) : 0;
        int rw = (cls & 2) ? (((row % 7) < 4) ? 1 : 2) : 0;
        int ch = (cls & 1) ? (((col / 7) < 4) ? 1 : 2) : 0;
        int cw = (cls & 2) ? (((col % 7) < 4) ? 1 : 2) : 0;
        float mask = ((rh * 3 + rw) != (ch * 3 + cw)) ? -100.0f : 0.0f;
        val = rbt[rpi[row * 49 + col] * NH_ + h] + mask;
    }
    tabP[t] = val;
}

// ======================= fused QKV + attention + projection ==========
__global__ __launch_bounds__(256, 3) void swin_mega_kernel(
    const float* __restrict__ x,       // (32,56,56,256)
    const float* __restrict__ qkvB,    // (768,)
    const __hip_bfloat16* __restrict__ wsQ,  // (768,256) bf16
    const __hip_bfloat16* __restrict__ wsP,  // (256,256) bf16
    const float* __restrict__ projB,   // (256,)
    const float* __restrict__ tabP,    // [4][8][64][64] bias+mask, padded
    float* __restrict__ out)           // (32,56,56,256)
{
    constexpr int SXS = 264;   // s_x/s_o row stride (el)
    constexpr int QKS = 40;    // q/k row stride (el); row = 80B, 16B-multiple
    constexpr int VTS = 56;    // vt row stride (el); row = 112B, 16B-multiple
    constexpr int PS  = 72;    // P row stride (el);  row = 144B, 16B-multiple
    constexpr int WVSZ = NTOK * PS;   // 3,528 el = 7,056 B — the max phase

    __shared__ alignas(16) __hip_bfloat16 s_x[NTOK * SXS];    // 25,872 B; reused as s_o
    __shared__ alignas(16) __hip_bfloat16 s_wv[4 * WVSZ];     // 28,224 B

    const int tid = threadIdx.x, wave = tid >> 6, lane = tid & 63;
    const int quad = lane >> 4, l16 = lane & 15;
    const int l32 = lane & 31, half = lane >> 5;
    const int win = blockIdx.x;
    const int b = win >> 6, wh = (win >> 3) & 7, wwi = win & 7;
    const int cls = ((wh == 7) ? 1 : 0) | ((wwi == 7) ? 2 : 0);

    __hip_bfloat16* wbuf = s_wv + wave * WVSZ;   // time-multiplexed region

    // stage window x -> bf16 LDS (shifted gather), cooperative, packed 8B stores
    for (int i = tid; i < NTOK * 64; i += 256) {
        int tok = i >> 6, f4 = (i & 63) * 4;
        int r = tok / 7, c = tok - r * 7;
        int hg = wh * 7 + r + 3; if (hg >= 56) hg -= 56;
        int wg = wwi * 7 + c + 3; if (wg >= 56) wg -= 56;
        float4 v = *(const float4*)(x + ((b * 56 + hg) * 56 + wg) * DIM_ + f4);
        union { ushort4 u4; __hip_bfloat16 h[4]; } pkst;
        pkst.h[0] = __float2bfloat16(v.x);
        pkst.h[1] = __float2bfloat16(v.y);
        pkst.h[2] = __float2bfloat16(v.z);
        pkst.h[3] = __float2bfloat16(v.w);
        *(ushort4*)(s_x + tok * SXS + f4) = pkst.u4;
    }
    __syncthreads();   // the only barrier before the epilogue

    const float qscale = 0.17677669529663687f;  // 1/sqrt(32)
    // clamped second-tile row (tokens 32..63 -> clamp >=49 to 0; results masked)
    const int r1 = (32 + l32 < NTOK) ? (32 + l32) : 0;
    const __hip_bfloat16* arow0 = s_x + l32 * SXS + half * 8;
    const __hip_bfloat16* arow1 = s_x + r1 * SXS + half * 8;

    // 32x32 QKV tile: C rows/cols per operand order chosen by caller
    auto gemm32 = [&](int nb, bool swapped, v16f& acc0, v16f& acc1) {
        const __hip_bfloat16* wrow = wsQ + (nb + l32) * DIM_ + half * 8;
        acc0 = zero_v16f(); acc1 = zero_v16f();
        #pragma unroll
        for (int kh = 0; kh < 2; ++kh) {
            v8s wf[8];
            #pragma unroll
            for (int k = 0; k < 8; ++k)
                wf[k] = *(const v8s*)(wrow + kh * 128 + k * 16);
            #pragma unroll
            for (int k = 0; k < 8; ++k) {
                v8s a0 = *(const v8s*)(arow0 + kh * 128 + k * 16);
                v8s a1 = *(const v8s*)(arow1 + kh * 128 + k * 16);
                if (!swapped) {
                    acc0 = MFMA32(a0, wf[k], acc0, 0, 0, 0);
                    acc1 = MFMA32(a1, wf[k], acc1, 0, 0, 0);
                } else {
                    acc0 = MFMA32(wf[k], a0, acc0, 0, 0, 0);
                    acc1 = MFMA32(wf[k], a1, acc1, 0, 0, 0);
                }
            }
        }
    };

    // PV outputs for both heads, kept in registers (all indices static).
    v4f ohacc[2][4][2];

    #pragma unroll
    for (int hp = 0; hp < 2; ++hp) {
        const int h = wave * 2 + hp;
        v16f acc0, acc1;
        v8s qa[4], kb[4], pb[2][2];

        // ---- Q tile -> wbuf[49][40] -> qa regs ----
        gemm32(h * 32, false, acc0, acc1);
        {
            float bias = qkvB[h * 32 + l32];
            #pragma unroll
            for (int rg = 0; rg < 16; ++rg) {
                int rowoff = (rg & 3) + 8 * (rg >> 2) + 4 * half;   // 0..31
                wbuf[rowoff * QKS + l32] =
                    __float2bfloat16((acc0[rg] + bias) * qscale);
                int tok1 = 32 + rowoff;
                if (tok1 < NTOK)
                    wbuf[tok1 * QKS + l32] =
                        __float2bfloat16((acc1[rg] + bias) * qscale);
            }
        }
        WAVE_FENCE();
        #pragma unroll
        for (int mt = 0; mt < 4; ++mt)
            qa[mt] = lds_frag(wbuf, mt * 16 + l16, QKS, quad * 8, NTOK);
        WAVE_FENCE();   // qa in regs before K overwrites region

        // ---- K tile -> wbuf[49][40] -> kb regs ----
        gemm32(256 + h * 32, false, acc0, acc1);
        {
            float bias = qkvB[256 + h * 32 + l32];
            #pragma unroll
            for (int rg = 0; rg < 16; ++rg) {
                int rowoff = (rg & 3) + 8 * (rg >> 2) + 4 * half;
                wbuf[rowoff * QKS + l32] = __float2bfloat16(acc0[rg] + bias);
                int tok1 = 32 + rowoff;
                if (tok1 < NTOK)
                    wbuf[tok1 * QKS + l32] = __float2bfloat16(acc1[rg] + bias);
            }
        }
        WAVE_FENCE();
        #pragma unroll
        for (int mt = 0; mt < 4; ++mt)
            kb[mt] = lds_frag(wbuf, mt * 16 + l16, QKS, quad * 8, NTOK);
        WAVE_FENCE();   // kb in regs before V overwrites region

        // ---- V tile (swapped -> VT layout) -> wbuf[32][56] -> pb regs ----
        // zero pad cols 49..55 (region holds stale data from K / prior P)
        for (int i = lane; i < 32 * 7; i += 64)
            wbuf[(i / 7) * VTS + 49 + (i % 7)] = __float2bfloat16(0.0f);
        gemm32(512 + h * 32, true, acc0, acc1);
        {
            const int nb = 512 + h * 32;
            const int tok1 = 32 + l32;           // masked >= 49
            #pragma unroll
            for (int rg = 0; rg < 16; ++rg) {
                int feat = (rg & 3) + 8 * (rg >> 2) + 4 * half;     // 0..31
                float bias = qkvB[nb + feat];
                wbuf[feat * VTS + l32] = __float2bfloat16(acc0[rg] + bias);
                if (tok1 < NTOK)
                    wbuf[feat * VTS + tok1] = __float2bfloat16(acc1[rg] + bias);
            }
        }
        WAVE_FENCE();
        #pragma unroll
        for (int nt = 0; nt < 2; ++nt) {
            const __hip_bfloat16* vr = wbuf + (nt * 16 + l16) * VTS;
            pb[nt][0] = *(const v8s*)(vr + quad * 8);
            pb[nt][1] = (quad == 3) ? zero_v8s() : *(const v8s*)(vr + 32 + quad * 8);
        }
        WAVE_FENCE();   // pb in regs before P overwrites region

        // ---- S^T = K·Q^T softmax -> P in wbuf[49][72] ----
        const float* tabh = tabP + (cls * NH_ + h) * 4096;   // [64][64]
        #pragma unroll
        for (int ntq = 0; ntq < 4; ++ntq) {
            const int qtok = ntq * 16 + l16;
            v4f tv[4];
            #pragma unroll
            for (int mt = 0; mt < 4; ++mt)
                tv[mt] = *(const v4f*)(tabh + qtok * 64 + mt * 16 + quad * 4);
            v4f st[4];
            #pragma unroll
            for (int mt = 0; mt < 4; ++mt) {
                v4f z = {0.f, 0.f, 0.f, 0.f};
                st[mt] = MFMA16(kb[mt], qa[ntq], z, 0, 0, 0);
            }
            float v[16];
            float rmax = -1e30f;
            #pragma unroll
            for (int mt = 0; mt < 4; ++mt)
                #pragma unroll
                for (int rg = 0; rg < 4; ++rg) {
                    float s = st[mt][rg] + tv[mt][rg];
                    v[mt * 4 + rg] = s;
                    rmax = fmaxf(rmax, s);
                }
            rmax = fmaxf(rmax, __shfl_xor(rmax, 16, 64));
            rmax = fmaxf(rmax, __shfl_xor(rmax, 32, 64));
            float rsum = 0.f;
            #pragma unroll
            for (int i = 0; i < 16; ++i) {
                float e = (v[i] <= -1e29f) ? 0.f : __expf(v[i] - rmax);
                v[i] = e;
                rsum += e;
            }
            rsum += __shfl_xor(rsum, 16, 64);
            rsum += __shfl_xor(rsum, 32, 64);
            if (qtok < NTOK) {
                float inv = 1.0f / rsum;
                #pragma unroll
                for (int mt = 0; mt < 4; ++mt) {
                    union { __hip_bfloat16 h4[4]; unsigned long long u; } pk;
                    #pragma unroll
                    for (int rg = 0; rg < 4; ++rg)
                        pk.h4[rg] = __float2bfloat16(v[mt * 4 + rg] * inv);
                    *(unsigned long long*)(wbuf + qtok * PS + mt * 16 + quad * 4) = pk.u;
                }
            }
        }
        WAVE_FENCE();

        // ---- PV: oh(49x32) = P @ v ; keep in registers ----
        #pragma unroll
        for (int mtile = 0; mtile < 4; ++mtile) {
            v8s pa0 = lds_frag(wbuf, mtile * 16 + l16, PS, quad * 8, NTOK);
            v8s pa1 = lds_frag(wbuf, mtile * 16 + l16, PS, 32 + quad * 8, NTOK);
            #pragma unroll
            for (int nt = 0; nt < 2; ++nt) {
                v4f z = {0.f, 0.f, 0.f, 0.f};
                v4f acc = MFMA16(pa0, pb[nt][0], z, 0, 0, 0);
                acc = MFMA16(pa1, pb[nt][1], acc, 0, 0, 0);
                ohacc[hp][mtile][nt] = acc;
            }
        }
        WAVE_FENCE();   // P reads done before next head's Q stores
    }

    // all waves done with s_x -> reuse as s_o [49][264]
    __syncthreads();
    __hip_bfloat16* s_o = s_x;

    #pragma unroll
    for (int hp = 0; hp < 2; ++hp) {
        const int h = wave * 2 + hp;
        #pragma unroll
        for (int mtile = 0; mtile < 4; ++mtile)
            #pragma unroll
            for (int nt = 0; nt < 2; ++nt)
                #pragma unroll
                for (int rg = 0; rg < 4; ++rg) {
                    int tok = mtile * 16 + quad * 4 + rg;
                    if (tok < NTOK)
                        s_o[tok * SXS + h * 32 + nt * 16 + l16] =
                            __float2bfloat16(ohacc[hp][mtile][nt][rg]);
                }
    }
    __syncthreads();

    // ---------- projection epilogue: wave owns t-quarter ----------
    // wf hoisted once per t (32 global loads/wave); af from LDS.
    {
        // output offsets for all 16 rows this lane covers (mt x rg)
        int ooff[4][4];
        #pragma unroll
        for (int mt = 0; mt < 4; ++mt)
            #pragma unroll
            for (int rg = 0; rg < 4; ++rg) {
                int row = mt * 16 + quad * 4 + rg;
                if (row < NTOK) {
                    int r = row / 7, c = row - r * 7;
                    int hg = wh * 7 + r + 3; if (hg >= 56) hg -= 56;
                    int wg = wwi * 7 + c + 3; if (wg >= 56) wg -= 56;
                    ooff[mt][rg] = ((b * 56 + hg) * 56 + wg) * DIM_;
                } else ooff[mt][rg] = -1;
            }

        #pragma unroll
        for (int tt = 0; tt < 4; ++tt) {
            const int t = wave * 4 + tt;
            const __hip_bfloat16* wrow = wsP + (t * 16 + l16) * DIM_;
            v8s wf[8];
            #pragma unroll
            for (int ks = 0; ks < 8; ++ks)
                wf[ks] = *(const v8s*)(wrow + ks * 32 + quad * 8);
            float pbv = projB[t * 16 + l16];

            #pragma unroll
            for (int mt = 0; mt < 4; ++mt) {
                v4f acc = {0.f, 0.f, 0.f, 0.f};
                #pragma unroll
                for (int ks = 0; ks < 8; ++ks) {
                    v8s af = lds_frag(s_o, mt * 16 + l16, SXS,
                                      ks * 32 + quad * 8, NTOK);
                    acc = MFMA16(af, wf[ks], acc, 0, 0, 0);
                }
                #pragma unroll
                for (int rg = 0; rg < 4; ++rg)
                    if (ooff[mt][rg] >= 0)
                        out[ooff[mt][rg] + t * 16 + l16] = acc[rg] + pbv;
            }
        }
    }
}

// ======================= fallback: previous fused kernel ==================
__global__ __launch_bounds__(256, 2) void swin_attn_fused(
    const float* __restrict__ x,
    const float* __restrict__ qkvB,
    const float* __restrict__ projB,
    const float* __restrict__ rbt,
    const int*   __restrict__ rpi,
    const __hip_bfloat16* __restrict__ wsQ,
    const __hip_bfloat16* __restrict__ wsP,
    const float* __restrict__ biasTab,   // class-0 rows of tabP (64x64) or null
    float*       __restrict__ out)
{
    constexpr int QKS = 40;
    constexpr int VTS = 72;
    constexpr int PS  = 72;
    constexpr int OS  = 264;
    constexpr int WVSZ = 6224;

    __shared__ alignas(16) __hip_bfloat16 s_wv[4 * WVSZ];
    __shared__ alignas(16) __hip_bfloat16 s_o[NTOK * OS];
    __shared__ int s_off[NTOK];
    __shared__ int s_reg[NTOK];

    const int tid  = threadIdx.x;
    const int wave = tid >> 6;
    const int lane = tid & 63;
    const int quad = lane >> 4;
    const int l16  = lane & 15;

    const int wid  = blockIdx.x;
    const int b    = wid >> 6;
    const int wIdx = wid & 63;
    const int wh   = wIdx >> 3;
    const int wwi  = wIdx & 7;

    if (tid < NTOK) {
        int r = tid / 7, c = tid - r * 7;
        int hs = wh * 7 + r, ws = wwi * 7 + c;
        int hg = hs + 3; if (hg >= 56) hg -= 56;
        int wg = ws + 3; if (wg >= 56) wg -= 56;
        s_off[tid] = ((b * 56 + hg) * 56 + wg) * DIM_;
        int rh = (hs < 49) ? 0 : ((hs < 53) ? 1 : 2);
        int rw = (ws < 49) ? 0 : ((ws < 53) ? 1 : 2);
        s_reg[tid] = rh * 3 + rw;
    }

    __hip_bfloat16* wq  = s_wv + wave * WVSZ;
    __hip_bfloat16* wk  = wq + NTOK * QKS;
    __hip_bfloat16* wvt = wq + 2 * NTOK * QKS;
    __hip_bfloat16* wp  = wq;

    for (int i = lane; i < 32 * 15; i += 64) {
        int f = i / 15, kk = 49 + (i % 15);
        wvt[f * VTS + kk] = __float2bfloat16(0.0f);
    }
    __syncthreads();

    const float qscale = 0.17677669529663687f;

    for (int hp = 0; hp < 2; ++hp) {
        const int h = wave * 2 + hp;
        LGKM_WAIT();

        for (int mh = 0; mh < 2; ++mh) {
            const int mbase = mh * 32;
            v8s at[2][8];
            #pragma unroll
            for (int sub = 0; sub < 2; ++sub) {
                int tok = mbase + sub * 16 + l16;
                const float* xr = (tok < NTOK) ? (x + s_off[tok]) : nullptr;
                #pragma unroll
                for (int ks = 0; ks < 8; ++ks)
                    at[sub][ks] = xr ? cvt8(xr + ks * 32 + quad * 8) : zero_v8s();
            }
            #pragma unroll
            for (int t = 0; t < 6; ++t) {
                int mat = t >> 1, ntile = t & 1;
                int nout = mat * 256 + h * 32 + ntile * 16 + l16;
                const __hip_bfloat16* wrow = wsQ + nout * DIM_;
                v4f a0 = {0.f, 0.f, 0.f, 0.f}, a1 = {0.f, 0.f, 0.f, 0.f};
                #pragma unroll
                for (int ks = 0; ks < 8; ++ks) {
                    v8s bfr = *(const v8s*)(wrow + ks * 32 + quad * 8);
                    a0 = MFMA16(at[0][ks], bfr, a0, 0, 0, 0);
                    a1 = MFMA16(at[1][ks], bfr, a1, 0, 0, 0);
                }
                float bias  = qkvB[nout];
                float scale = (mat == 0) ? qscale : 1.0f;
                #pragma unroll
                for (int sub = 0; sub < 2; ++sub) {
                    v4f acc = sub ? a1 : a0;
                    #pragma unroll
                    for (int rg = 0; rg < 4; ++rg) {
                        int row = mbase + sub * 16 + quad * 4 + rg;
                        if (row < NTOK) {
                            float val = (acc[rg] + bias) * scale;
                            int col = ntile * 16 + l16;
                            __hip_bfloat16 bv = __float2bfloat16(val);
                            if (mat == 0)      wq[row * QKS + col] = bv;
                            else if (mat == 1) wk[row * QKS + col] = bv;
                            else               wvt[col * VTS + row] = bv;
                        }
                    }
                }
            }
        }
        LGKM_WAIT();

        v8s qa[4], kb[4];
        #pragma unroll
        for (int i = 0; i < 4; ++i) {
            qa[i] = lds_frag(wq, i * 16 + l16, QKS, quad * 8, NTOK);
            kb[i] = lds_frag(wk, i * 16 + l16, QKS, quad * 8, NTOK);
        }
        int regc[4];
        #pragma unroll
        for (int nt = 0; nt < 4; ++nt) {
            int col = nt * 16 + l16;
            regc[nt] = (col < NTOK) ? s_reg[col] : -1;
        }
        LGKM_WAIT();
        const float* tabh = biasTab ? (biasTab + h * 4096) : nullptr;
        #pragma unroll
        for (int mtile = 0; mtile < 4; ++mtile) {
            v4f sa[4];
            #pragma unroll
            for (int nt = 0; nt < 4; ++nt) {
                v4f z = {0.f, 0.f, 0.f, 0.f};
                sa[nt] = MFMA16(qa[mtile], kb[nt], z, 0, 0, 0);
            }
            #pragma unroll
            for (int rg = 0; rg < 4; ++rg) {
                int row = mtile * 16 + quad * 4 + rg;
                bool rok = row < NTOK;
                int rr = rok ? s_reg[row] : -2;
                float v[4];
                float rmax = -1e30f;
                #pragma unroll
                for (int nt = 0; nt < 4; ++nt) {
                    int col = nt * 16 + l16;
                    float s = -1e30f;
                    if (rok && col < NTOK) {
                        float bv = tabh ? tabh[row * 64 + col]
                                        : rbt[rpi[row * 49 + col] * NH_ + h];
                        s = sa[nt][rg] + bv;
                        if (rr != regc[nt]) s -= 100.0f;
                    }
                    v[nt] = s;
                    rmax = fmaxf(rmax, s);
                }
                #pragma unroll
                for (int mm = 8; mm >= 1; mm >>= 1)
                    rmax = fmaxf(rmax, __shfl_xor(rmax, mm, 64));
                float rsum = 0.f;
                #pragma unroll
                for (int nt = 0; nt < 4; ++nt) {
                    float e = (v[nt] <= -1e29f) ? 0.f : __expf(v[nt] - rmax);
                    v[nt] = e;
                    rsum += e;
                }
                #pragma unroll
                for (int mm = 8; mm >= 1; mm >>= 1)
                    rsum += __shfl_xor(rsum, mm, 64);
                if (rok) {
                    float inv = 1.0f / rsum;
                    #pragma unroll
                    for (int nt = 0; nt < 4; ++nt)
                        wp[row * PS + nt * 16 + l16] = __float2bfloat16(v[nt] * inv);
                }
            }
        }
        LGKM_WAIT();

        v8s pb[2][2];
        #pragma unroll
        for (int nt = 0; nt < 2; ++nt)
            #pragma unroll
            for (int ks = 0; ks < 2; ++ks)
                pb[nt][ks] = *(const v8s*)(wvt + (nt * 16 + l16) * VTS + ks * 32 + quad * 8);
        #pragma unroll
        for (int mtile = 0; mtile < 4; ++mtile) {
            v8s pa0 = lds_frag(wp, mtile * 16 + l16, PS, quad * 8, NTOK);
            v8s pa1 = lds_frag(wp, mtile * 16 + l16, PS, 32 + quad * 8, NTOK);
            #pragma unroll
            for (int nt = 0; nt < 2; ++nt) {
                v4f z = {0.f, 0.f, 0.f, 0.f};
                v4f acc = MFMA16(pa0, pb[nt][0], z, 0, 0, 0);
                acc = MFMA16(pa1, pb[nt][1], acc, 0, 0, 0);
                #pragma unroll
                for (int rg = 0; rg < 4; ++rg) {
                    int row = mtile * 16 + quad * 4 + rg;
                    if (row < NTOK)
                        s_o[row * OS + h * 32 + nt * 16 + l16] = __float2bfloat16(acc[rg]);
                }
            }
        }
    }
    __syncthreads();

    {
        int m0 = wave * 16;
        v8s af[8];
        #pragma unroll
        for (int ks = 0; ks < 8; ++ks)
            af[ks] = lds_frag(s_o, m0 + l16, OS, ks * 32 + quad * 8, NTOK);
        #pragma unroll
        for (int t = 0; t < 16; ++t) {
            const __hip_bfloat16* wrow = wsP + (t * 16 + l16) * DIM_;
            v4f acc = {0.f, 0.f, 0.f, 0.f};
            #pragma unroll
            for (int ks = 0; ks < 8; ++ks) {
                v8s bfr = *(const v8s*)(wrow + ks * 32 + quad * 8);
                acc = MFMA16(af[ks], bfr, acc, 0, 0, 0);
            }
            float pbv = projB[t * 16 + l16];
            #pragma unroll
            for (int rg = 0; rg < 4; ++rg) {
                int row = m0 + quad * 4 + rg;
                if (row < NTOK)
                    out[s_off[row] + t * 16 + l16] = acc[rg] + pbv;
            }
        }
    }
}

extern "C" void kernel_launch(void* const* d_in, const int* in_sizes, int n_in,
                              void* d_out, int out_size, void* d_ws, size_t ws_size,
                              hipStream_t stream) {
    const float* x     = (const float*)d_in[0];
    const float* qkvW  = (const float*)d_in[1];
    const float* qkvB  = (const float*)d_in[2];
    const float* projW = (const float*)d_in[3];
    const float* projB = (const float*)d_in[4];
    const float* rbt   = (const float*)d_in[5];
    const int*   rpi   = (const int*)d_in[6];
    float* o = (float*)d_out;

    __hip_bfloat16* wsQ = (__hip_bfloat16*)d_ws;
    __hip_bfloat16* wsP = (__hip_bfloat16*)((char*)d_ws + WSP_B);
    float* tabP         = (float*)((char*)d_ws + TAB_B);

    const int prepBlocks = (NQKV + NPRJ + NTABP + 255) / 256;

    if (ws_size >= NEED_TAB) {
        prep_kernel<<<prepBlocks, 256, 0, stream>>>(qkvW, projW, rbt, rpi,
                                                    wsQ, wsP, tabP, 1);
        swin_mega_kernel<<<2048, 256, 0, stream>>>(x, qkvB, wsQ, wsP, projB,
                                                   tabP, o);
    } else {
        prep_kernel<<<prepBlocks, 256, 0, stream>>>(qkvW, projW, rbt, rpi,
                                                    wsQ, wsP, tabP, 0);
        swin_attn_fused<<<2048, 256, 0, stream>>>(x, qkvB, projB, rbt, rpi,
                                                  wsQ, wsP, nullptr, o);
    }
}